// Round 2
// baseline (609.274 us; speedup 1.0000x reference)
//
#include <hip/hip_runtime.h>
#include <hip/hip_bf16.h>
#include <cstddef>

// ---------------- problem constants ----------------
#define DMODEL  768
#define DINNER  1536
#define DSTATE  64
#define NH      24
#define HD      64
#define CONVD   1664      // DINNER + 2*DSTATE
#define DINPROJ 3224      // 2*DINNER + 2*DSTATE + NH
#define SEQ     4096
#define BSZ     2
#define NTOK    8192      // BSZ*SEQ
#define NCHUNK  64        // SEQ/64
#define EPSF    1e-5f

typedef __attribute__((ext_vector_type(8))) short  short8;
typedef __attribute__((ext_vector_type(4))) float  f32x4;

// ---------------- helpers ----------------
__device__ __forceinline__ unsigned short f2bf(float f) {
  union { float f; unsigned int u; } v; v.f = f;
  unsigned int r = v.u + 0x7fffu + ((v.u >> 16) & 1u);   // RNE
  return (unsigned short)(r >> 16);
}
__device__ __forceinline__ float bf2f(unsigned short u) {
  union { unsigned int i; float f; } v; v.i = ((unsigned int)u) << 16; return v.f;
}
__device__ __forceinline__ unsigned long long pack4bf(float a, float b, float c, float d) {
  return (unsigned long long)(f2bf(a) | ((unsigned int)f2bf(b) << 16))
       | ((unsigned long long)(f2bf(c) | ((unsigned int)f2bf(d) << 16)) << 32);
}
__device__ __forceinline__ void unpack4(const unsigned short* p, float* o) {
  const unsigned int* q = (const unsigned int*)p;   // p must be 4B-aligned
  unsigned int a = q[0], b = q[1];
  union { unsigned int u; float f; } c0, c1, c2, c3;
  c0.u = a << 16; c1.u = a & 0xffff0000u;
  c2.u = b << 16; c3.u = b & 0xffff0000u;
  o[0] = c0.f; o[1] = c1.f; o[2] = c2.f; o[3] = c3.f;
}
__device__ __forceinline__ float sigm(float x) { return 1.f / (1.f + __expf(-x)); }

// ---------------- LayerNorm -> bf16 ----------------
__global__ __launch_bounds__(256) void k_ln(const float* __restrict__ x,
    const float* __restrict__ w, const float* __restrict__ b,
    unsigned short* __restrict__ xn)
{
  __shared__ float red[4];
  const int row = blockIdx.x, tid = threadIdx.x;
  const float* xr = x + (size_t)row * DMODEL;
  float v[3]; float s = 0.f;
  #pragma unroll
  for (int q = 0; q < 3; q++) { v[q] = xr[q*256 + tid]; s += v[q]; }
  #pragma unroll
  for (int off = 32; off; off >>= 1) s += __shfl_down(s, off);
  if ((tid & 63) == 0) red[tid >> 6] = s;
  __syncthreads();
  const float mu = (red[0] + red[1] + red[2] + red[3]) * (1.f / DMODEL);
  __syncthreads();
  float s2 = 0.f;
  #pragma unroll
  for (int q = 0; q < 3; q++) { float d = v[q] - mu; s2 += d * d; }
  #pragma unroll
  for (int off = 32; off; off >>= 1) s2 += __shfl_down(s2, off);
  if ((tid & 63) == 0) red[tid >> 6] = s2;
  __syncthreads();
  const float rs = rsqrtf((red[0] + red[1] + red[2] + red[3]) * (1.f / DMODEL) + EPSF);
  unsigned short* xo = xn + (size_t)row * DMODEL;
  #pragma unroll
  for (int q = 0; q < 3; q++) {
    int col = q*256 + tid;
    xo[col] = f2bf((v[q] - mu) * rs * w[col] + b[col]);
  }
}

// ---------------- W[K][N] fp32 -> Wt[N][K] bf16 (tiled transpose) ----------------
__global__ __launch_bounds__(256) void k_wtrans(const float* __restrict__ W,
    unsigned short* __restrict__ Wt, int K, int N)
{
  __shared__ float tile[32][33];
  const int tid = threadIdx.x;
  const int tx = tid & 31, ty = tid >> 5;           // 32 x 8
  const int n0 = blockIdx.x * 32, k0 = blockIdx.y * 32;
  #pragma unroll
  for (int r = 0; r < 4; r++) {
    int k = k0 + ty + 8*r;
    if (k < K && n0 + tx < N) tile[ty + 8*r][tx] = W[(size_t)k * N + n0 + tx];
  }
  __syncthreads();
  #pragma unroll
  for (int r = 0; r < 4; r++) {
    int n = n0 + ty + 8*r, k = k0 + tx;
    if (n < N && k < K) Wt[(size_t)n * K + k] = f2bf(tile[tx][ty + 8*r]);
  }
}

// ---------------- bf16 MFMA GEMM: C[M][N] = A[M][K] @ Bt[N][K]^T ----------------
// epi: 0 plain, 1 sigmoid(C+bias[n]), 2 C+bias[n]+resid[m][n].  Cb!=null -> bf16 out.
__global__ __launch_bounds__(256) void k_gemm(const unsigned short* __restrict__ A,
    const unsigned short* __restrict__ Bt, float* __restrict__ C,
    unsigned short* __restrict__ Cb,
    int M, int N, int K, int epi, const float* __restrict__ bias,
    const float* __restrict__ resid)
{
  __shared__ alignas(16) unsigned short As[128][40];
  __shared__ alignas(16) unsigned short Bs[128][40];
  const int tid = threadIdx.x;
  const int m0 = blockIdx.y * 128, n0 = blockIdx.x * 128;
  const int lane = tid & 63, wv = tid >> 6;
  const int wm = (wv >> 1) * 64, wn = (wv & 1) * 64;
  const int l15 = lane & 15, lq = lane >> 4;
  f32x4 acc[4][4];
  #pragma unroll
  for (int i = 0; i < 4; i++)
    #pragma unroll
    for (int j = 0; j < 4; j++) acc[i][j] = (f32x4){0.f, 0.f, 0.f, 0.f};

  const int rowA = tid >> 2, kqA = (tid & 3) * 8;
  for (int k0 = 0; k0 < K; k0 += 32) {
    __syncthreads();
    #pragma unroll
    for (int it = 0; it < 2; it++) {
      int row = rowA + it * 64;
      int4 va = *(const int4*)(A + (size_t)(m0 + row) * K + k0 + kqA);
      *(int4*)(&As[row][kqA]) = va;
      int nrow = n0 + row;
      int4 vb = make_int4(0, 0, 0, 0);
      if (nrow < N) vb = *(const int4*)(Bt + (size_t)nrow * K + k0 + kqA);
      *(int4*)(&Bs[row][kqA]) = vb;
    }
    __syncthreads();
    short8 a8[4], b8[4];
    #pragma unroll
    for (int mi = 0; mi < 4; mi++) a8[mi] = *(const short8*)(&As[wm + 16*mi + l15][lq * 8]);
    #pragma unroll
    for (int ni = 0; ni < 4; ni++) b8[ni] = *(const short8*)(&Bs[wn + 16*ni + l15][lq * 8]);
    #pragma unroll
    for (int mi = 0; mi < 4; mi++)
      #pragma unroll
      for (int ni = 0; ni < 4; ni++)
        acc[mi][ni] = __builtin_amdgcn_mfma_f32_16x16x32_bf16(a8[mi], b8[ni], acc[mi][ni], 0, 0, 0);
  }
  #pragma unroll
  for (int mi = 0; mi < 4; mi++) {
    #pragma unroll
    for (int r = 0; r < 4; r++) {
      int row = m0 + wm + 16*mi + lq*4 + r;
      #pragma unroll
      for (int ni = 0; ni < 4; ni++) {
        int col = n0 + wn + 16*ni + l15;
        if (col < N) {
          float vv = acc[mi][ni][r];
          if (epi == 1)      vv = sigm(vv + bias[col]);
          else if (epi == 2) vv = vv + bias[col] + resid[(size_t)row * N + col];
          if (Cb) Cb[(size_t)row * N + col] = f2bf(vv);
          else    C [(size_t)row * N + col] = vv;
        }
      }
    }
  }
}

// ---------------- causal conv1d (K=4) + SiLU over xBC cols (bf16 in/out) ---------
__global__ __launch_bounds__(256) void k_conv(const unsigned short* __restrict__ zx,
    const float* __restrict__ cw, const float* __restrict__ cb,
    unsigned short* __restrict__ out)
{
  size_t idx = (size_t)blockIdx.x * 256 + threadIdx.x;   // NTOK*CONVD total
  int c = (int)(idx % CONVD);
  size_t bt = idx / CONVD;
  int t = (int)(bt % SEQ);
  const unsigned short* base = zx + bt * DINPROJ + DINNER + c;
  float acc = cb[c];
  #pragma unroll
  for (int k = 0; k < 4; k++) {
    int tt = t - 3 + k;
    if (tt >= 0) acc += bf2f(base[(ptrdiff_t)(k - 3) * DINPROJ]) * cw[c * 4 + k];
  }
  out[bt * CONVD + c] = f2bf(acc * sigm(acc));
}

// ---------------- SSD pass 1: chunk states S[bh,c][n][p] fp32, chunk decay -------
__global__ __launch_bounds__(256) void k_chunkstate(const unsigned short* __restrict__ zx,
    const unsigned short* __restrict__ xbcc, const float* __restrict__ dt_bias,
    const float* __restrict__ A_log, float* __restrict__ S, float* __restrict__ CD)
{
  const int c = blockIdx.x, bh = blockIdx.y;
  const int b = bh / NH, h = bh % NH;
  const int tid = threadIdx.x;
  __shared__ float dts[64], Lc[64], wv_[64];
  __shared__ alignas(16) unsigned short Bw[64][64], Xs[64][64];
  if (tid < 64) {
    int t = c * 64 + tid;
    float xx = bf2f(zx[((size_t)(b * SEQ + t)) * DINPROJ + (DINNER + CONVD) + h]) + dt_bias[h];
    dts[tid] = (xx > 15.f) ? xx : log1pf(__expf(xx));
  }
  __syncthreads();
  if (tid == 0) {
    float Ah = -__expf(A_log[h]);
    float run = 0.f;
    for (int i = 0; i < 64; i++) { run += dts[i] * Ah; Lc[i] = run; }
    CD[bh * 64 + c] = __expf(run);
  }
  __syncthreads();
  if (tid < 64) wv_[tid] = __expf(Lc[63] - Lc[tid]) * dts[tid];
  __syncthreads();
  #pragma unroll
  for (int it = 0; it < 4; it++) {
    int i4 = tid + 256 * it;
    int s = i4 >> 4, n04 = (i4 & 15) * 4;
    size_t rb = ((size_t)(b * SEQ) + c * 64 + s) * CONVD;
    float w = wv_[s];
    unsigned short us[4]; float f[4];
    *(unsigned long long*)us = *(const unsigned long long*)(xbcc + rb + DINNER + n04);
    #pragma unroll
    for (int j = 0; j < 4; j++) f[j] = bf2f(us[j]) * w;
    *(unsigned long long*)(&Bw[s][n04]) = pack4bf(f[0], f[1], f[2], f[3]);
    *(unsigned long long*)(&Xs[s][n04]) = *(const unsigned long long*)(xbcc + rb + h * HD + n04);
  }
  __syncthreads();
  const int tn = tid >> 4, tp = tid & 15;
  float acc[4][4] = {};
  for (int k = 0; k < 64; k++) {
    float av[4], bv[4];
    unpack4(&Bw[k][4 * tn], av);
    unpack4(&Xs[k][4 * tp], bv);
    #pragma unroll
    for (int r = 0; r < 4; r++)
      #pragma unroll
      for (int j = 0; j < 4; j++) acc[r][j] += av[r] * bv[j];
  }
  size_t sb = ((size_t)bh * 64 + c) * 4096;
  #pragma unroll
  for (int r = 0; r < 4; r++) {
    float4 o = make_float4(acc[r][0], acc[r][1], acc[r][2], acc[r][3]);
    *(float4*)(S + sb + (size_t)(4 * tn + r) * 64 + 4 * tp) = o;
  }
}

// ---------------- SSD pass 2: chunk-level recurrence (in-place S -> G) -----------
__global__ __launch_bounds__(256) void k_chunkrec(float* __restrict__ S,
    const float* __restrict__ CD)
{
  const int bh = blockIdx.x >> 4, part = blockIdx.x & 15;
  const int e = part * 256 + threadIdx.x;
  float g = 0.f;
  size_t base = (size_t)bh * 64 * 4096 + e;
  for (int c = 0; c < 64; c++) {
    size_t ad = base + (size_t)c * 4096;
    float sv = S[ad];
    float pc = CD[bh * 64 + c];
    S[ad] = g;               // slot c now holds G_c (state before chunk c)
    g = pc * g + sv;
  }
}

// ---------------- SSD pass 3: per-chunk outputs (bf16 Y out) ---------------------
__global__ __launch_bounds__(256) void k_chunkout(const unsigned short* __restrict__ zx,
    const unsigned short* __restrict__ xbcc, const float* __restrict__ S,
    const float* __restrict__ dt_bias, const float* __restrict__ A_log,
    const float* __restrict__ Dp, unsigned short* __restrict__ Y)
{
  const int c = blockIdx.x, bh = blockIdx.y;
  const int b = bh / NH, h = bh % NH;
  const int tid = threadIdx.x;
  __shared__ float dts[64], Lc[64], ein[64];
  __shared__ alignas(16) unsigned short Cn[64][64], Bn[64][64], Xs[64][64], Pt[64][64];
  __shared__ alignas(16) float Gs[64][64];
  if (tid < 64) {
    int t = c * 64 + tid;
    float xx = bf2f(zx[((size_t)(b * SEQ + t)) * DINPROJ + (DINNER + CONVD) + h]) + dt_bias[h];
    dts[tid] = (xx > 15.f) ? xx : log1pf(__expf(xx));
  }
  __syncthreads();
  if (tid == 0) {
    float Ah = -__expf(A_log[h]);
    float run = 0.f;
    for (int i = 0; i < 64; i++) { run += dts[i] * Ah; Lc[i] = run; }
  }
  __syncthreads();
  if (tid < 64) ein[tid] = __expf(Lc[tid]);
  size_t gslot = ((size_t)bh * 64 + c) * 4096;
  #pragma unroll
  for (int it = 0; it < 4; it++) {
    int i4 = tid + 256 * it;
    int rr = i4 >> 4, q4 = (i4 & 15) * 4;
    size_t rb = ((size_t)(b * SEQ) + c * 64 + rr) * CONVD;
    const unsigned short* pC = xbcc + rb + (DINNER + DSTATE) + q4;
    Cn[q4+0][rr] = pC[0]; Cn[q4+1][rr] = pC[1]; Cn[q4+2][rr] = pC[2]; Cn[q4+3][rr] = pC[3];
    const unsigned short* pB = xbcc + rb + DINNER + q4;
    Bn[q4+0][rr] = pB[0]; Bn[q4+1][rr] = pB[1]; Bn[q4+2][rr] = pB[2]; Bn[q4+3][rr] = pB[3];
    *(unsigned long long*)(&Xs[rr][q4]) = *(const unsigned long long*)(xbcc + rb + h * HD + q4);
    float4 vG = *(const float4*)(S + gslot + (size_t)i4 * 4);
    *(float4*)(&Gs[0][0] + (size_t)i4 * 4) = vG;
  }
  __syncthreads();
  // G[i][s] = sum_n C[i][n] B[s][n];  P[i][s] = mask * G * exp(Lc[i]-Lc[s]) * dt[s]
  {
    const int ta = tid & 15, tb = tid >> 4;
    float g[4][4] = {};
    for (int k = 0; k < 64; k++) {
      float cv[4], bv[4];
      unpack4(&Cn[k][4 * ta], cv);
      unpack4(&Bn[k][4 * tb], bv);
      #pragma unroll
      for (int r = 0; r < 4; r++)
        #pragma unroll
        for (int j = 0; j < 4; j++) g[r][j] += cv[r] * bv[j];
    }
    #pragma unroll
    for (int r = 0; r < 4; r++)
      #pragma unroll
      for (int j = 0; j < 4; j++) {
        int i = 4 * ta + r, s = 4 * tb + j;
        float p = 0.f;
        if (s <= i) p = g[r][j] * __expf(Lc[i] - Lc[s]) * dts[s];
        Pt[s][i] = f2bf(p);
      }
  }
  __syncthreads();
  // Y[i][p] = sum_s P[i][s] x[s][p]  +  ein[i] * sum_n C[i][n] G[n][p]  +  D*x[i][p]
  {
    const int tiq = tid >> 4, tp = tid & 15;
    float a1[4][4] = {}, a2[4][4] = {};
    for (int k = 0; k < 64; k++) {
      float pv[4], xv[4], cv[4];
      unpack4(&Pt[k][4 * tiq], pv);
      unpack4(&Xs[k][4 * tp], xv);
      unpack4(&Cn[k][4 * tiq], cv);
      float4 gr = *(const float4*)(&Gs[k][4 * tp]);
      float gv[4] = {gr.x, gr.y, gr.z, gr.w};
      #pragma unroll
      for (int r = 0; r < 4; r++)
        #pragma unroll
        for (int j = 0; j < 4; j++) {
          a1[r][j] += pv[r] * xv[j];
          a2[r][j] += cv[r] * gv[j];
        }
    }
    float Dh = Dp[h];
    #pragma unroll
    for (int r = 0; r < 4; r++) {
      int i = 4 * tiq + r;
      float ei = ein[i];
      float xq[4];
      unpack4(&Xs[i][4 * tp], xq);
      float o0 = a1[r][0] + ei * a2[r][0] + Dh * xq[0];
      float o1 = a1[r][1] + ei * a2[r][1] + Dh * xq[1];
      float o2 = a1[r][2] + ei * a2[r][2] + Dh * xq[2];
      float o3 = a1[r][3] + ei * a2[r][3] + Dh * xq[3];
      *(unsigned long long*)(Y + ((size_t)(b * SEQ) + c * 64 + i) * DINNER + h * HD + 4 * tp)
          = pack4bf(o0, o1, o2, o3);
    }
  }
}

// ---------------- y*silu(z), RMSNorm -> bf16 -------------------------------------
__global__ __launch_bounds__(256) void k_fuse(const unsigned short* __restrict__ Y,
    const unsigned short* __restrict__ ZX, const float* __restrict__ rw,
    unsigned short* __restrict__ YN)
{
  __shared__ float red[4];
  const int row = blockIdx.x, tid = threadIdx.x;
  const unsigned short* yr = Y + (size_t)row * DINNER;
  const unsigned short* zr = ZX + (size_t)row * DINPROJ;
  float v[6]; float s2 = 0.f;
  #pragma unroll
  for (int q = 0; q < 6; q++) {
    int col = q * 256 + tid;
    float z = bf2f(zr[col]);
    float yv = bf2f(yr[col]) * (z * sigm(z));
    v[q] = yv; s2 += yv * yv;
  }
  #pragma unroll
  for (int off = 32; off; off >>= 1) s2 += __shfl_down(s2, off);
  if ((tid & 63) == 0) red[tid >> 6] = s2;
  __syncthreads();
  const float rs = rsqrtf((red[0] + red[1] + red[2] + red[3]) * (1.f / DINNER) + EPSF);
  unsigned short* yo = YN + (size_t)row * DINNER;
  #pragma unroll
  for (int q = 0; q < 6; q++) {
    int col = q * 256 + tid;
    yo[col] = f2bf(v[q] * rs * rw[col]);
  }
}

// ---------------- yg = bf16(yproj * gate) ----------------------------------------
__global__ __launch_bounds__(256) void k_gatemul(const float* __restrict__ YP,
    const float* __restrict__ G, unsigned short* __restrict__ YG)
{
  size_t idx = (size_t)blockIdx.x * 256 + threadIdx.x;
  YG[idx] = f2bf(YP[idx] * G[idx]);
}

// ---------------- launch ----------------------------------------------------------
extern "C" void kernel_launch(void* const* d_in, const int* in_sizes, int n_in,
                              void* d_out, int out_size, void* d_ws, size_t ws_size,
                              hipStream_t stream)
{
  const float* x         = (const float*)d_in[0];
  const float* ln_w      = (const float*)d_in[1];
  const float* ln_b      = (const float*)d_in[2];
  const float* in_proj_w = (const float*)d_in[3];
  const float* conv_w    = (const float*)d_in[4];
  const float* conv_b    = (const float*)d_in[5];
  const float* dt_bias   = (const float*)d_in[6];
  const float* A_log     = (const float*)d_in[7];
  const float* D_param   = (const float*)d_in[8];
  const float* rms_w     = (const float*)d_in[9];
  const float* out_proj_w= (const float*)d_in[10];
  const float* gate_w    = (const float*)d_in[11];
  const float* gate_b    = (const float*)d_in[12];
  const float* out_w     = (const float*)d_in[13];
  const float* out_b     = (const float*)d_in[14];
  float* out = (float*)d_out;
  char* ws = (char*)d_ws;

  // ---- workspace layout (bytes). peak = 177,848,320 B (~170 MB) ----
  // live:   XN 12.6M | WIT 5.0M | WGT 1.2M | WOPT 2.4M | WOT 1.2M |
  //         ZXb 52.8M(bf16) | XBCCb 27.3M(bf16) | SG 50.3M(f32) | CD 12K | Yb 25.2M(bf16)
  // overlays (into dead regions):
  //         YN -> SG region; GATE/YPROJ -> ZXb region; YG -> XBCCb region
  const size_t WS_NEEDED = 177848320ull;
  if (ws_size < WS_NEEDED) return;   // diagnostic: output stays poisoned instead of faulting

  unsigned short* XN    = (unsigned short*)(ws + 0);
  unsigned short* WIT   = (unsigned short*)(ws + 12582912);
  unsigned short* WGT   = (unsigned short*)(ws + 17534976);
  unsigned short* WOPT  = (unsigned short*)(ws + 18714624);
  unsigned short* WOT   = (unsigned short*)(ws + 21073920);
  unsigned short* ZXb   = (unsigned short*)(ws + 22253568);   // 8192x3224 bf16
  unsigned short* XBCCb = (unsigned short*)(ws + 75075584);   // 8192x1664 bf16
  float*          SG    = (float*)(ws + 102338560);           // 3072x4096 f32
  float*          CD    = (float*)(ws + 152670208);           // 3072 f32
  unsigned short* Yb    = (unsigned short*)(ws + 152682496);  // 8192x1536 bf16
  // overlays:
  unsigned short* YN    = (unsigned short*)(ws + 102338560);  // in SG region (dead after chunkout)
  float*          GATE  = (float*)(ws + 22253568);            // in ZXb region (dead after fuse)
  float*          YPROJ = (float*)(ws + 47419392);            // in ZXb region
  unsigned short* YG    = (unsigned short*)(ws + 75075584);   // in XBCCb region (dead after chunkout)

  // 1) weight converts (bf16, transposed for TN GEMM)
  k_wtrans<<<dim3(101, 24), 256, 0, stream>>>(in_proj_w,  WIT,  768,  3224);
  k_wtrans<<<dim3(24, 24),  256, 0, stream>>>(gate_w,     WGT,  768,  768);
  k_wtrans<<<dim3(24, 48),  256, 0, stream>>>(out_proj_w, WOPT, 1536, 768);
  k_wtrans<<<dim3(24, 24),  256, 0, stream>>>(out_w,      WOT,  768,  768);
  // 2) layernorm
  k_ln<<<NTOK, 256, 0, stream>>>(x, ln_w, ln_b, XN);
  // 3) in_proj GEMM -> zxbcdt (bf16)
  k_gemm<<<dim3(26, 64), 256, 0, stream>>>(XN, WIT, nullptr, ZXb, NTOK, DINPROJ, DMODEL, 0, nullptr, nullptr);
  // 4) causal conv + silu (bf16 -> bf16)
  k_conv<<<(NTOK * CONVD) / 256, 256, 0, stream>>>(ZXb, conv_w, conv_b, XBCCb);
  // 5-7) SSD scan
  k_chunkstate<<<dim3(NCHUNK, BSZ * NH), 256, 0, stream>>>(ZXb, XBCCb, dt_bias, A_log, SG, CD);
  k_chunkrec<<<BSZ * NH * 16, 256, 0, stream>>>(SG, CD);
  k_chunkout<<<dim3(NCHUNK, BSZ * NH), 256, 0, stream>>>(ZXb, XBCCb, SG, dt_bias, A_log, D_param, Yb);
  // 8) y*silu(z) + RMSNorm -> bf16 (YN lands in dead SG region)
  k_fuse<<<NTOK, 256, 0, stream>>>(Yb, ZXb, rms_w, YN);
  // 9) gate GEMM (sigmoid epilogue) -> dead ZXb region
  k_gemm<<<dim3(6, 64), 256, 0, stream>>>(XN, WGT, GATE, nullptr, NTOK, DMODEL, DMODEL, 1, gate_b, nullptr);
  // 10) out_proj GEMM
  k_gemm<<<dim3(6, 64), 256, 0, stream>>>(YN, WOPT, YPROJ, nullptr, NTOK, DMODEL, DINNER, 0, nullptr, nullptr);
  // 11) gate multiply -> bf16
  k_gatemul<<<(NTOK * DMODEL) / 256, 256, 0, stream>>>(YPROJ, GATE, YG);
  // 12) final GEMM + bias + residual -> d_out
  k_gemm<<<dim3(6, 64), 256, 0, stream>>>(YG, WOT, out, nullptr, NTOK, DMODEL, DMODEL, 2, out_b, x);
}

// Round 3
// 526.325 us; speedup vs baseline: 1.1576x; 1.1576x over previous
//
#include <hip/hip_runtime.h>
#include <hip/hip_bf16.h>
#include <cstddef>

// ---------------- problem constants ----------------
#define DMODEL  768
#define DINNER  1536
#define DSTATE  64
#define NH      24
#define HD      64
#define CONVD   1664      // DINNER + 2*DSTATE
#define DINPROJ 3224      // 2*DINNER + 2*DSTATE + NH
#define SEQ     4096
#define BSZ     2
#define NTOK    8192      // BSZ*SEQ
#define NCHUNK  64        // SEQ/64
#define EPSF    1e-5f
#define LP      72        // LDS pitch (shorts): 36 dwords/row -> +4 banks/row, b128 reads spread evenly

typedef __attribute__((ext_vector_type(8))) short  short8;
typedef __attribute__((ext_vector_type(4))) float  f32x4;

// ---------------- helpers ----------------
__device__ __forceinline__ unsigned short f2bf(float f) {
  union { float f; unsigned int u; } v; v.f = f;
  unsigned int r = v.u + 0x7fffu + ((v.u >> 16) & 1u);   // RNE
  return (unsigned short)(r >> 16);
}
__device__ __forceinline__ float bf2f(unsigned short u) {
  union { unsigned int i; float f; } v; v.i = ((unsigned int)u) << 16; return v.f;
}
__device__ __forceinline__ float sigm(float x) { return 1.f / (1.f + __expf(-x)); }

// ---------------- LayerNorm -> bf16 ----------------
__global__ __launch_bounds__(256) void k_ln(const float* __restrict__ x,
    const float* __restrict__ w, const float* __restrict__ b,
    unsigned short* __restrict__ xn)
{
  __shared__ float red[4];
  const int row = blockIdx.x, tid = threadIdx.x;
  const float* xr = x + (size_t)row * DMODEL;
  float v[3]; float s = 0.f;
  #pragma unroll
  for (int q = 0; q < 3; q++) { v[q] = xr[q*256 + tid]; s += v[q]; }
  #pragma unroll
  for (int off = 32; off; off >>= 1) s += __shfl_down(s, off);
  if ((tid & 63) == 0) red[tid >> 6] = s;
  __syncthreads();
  const float mu = (red[0] + red[1] + red[2] + red[3]) * (1.f / DMODEL);
  __syncthreads();
  float s2 = 0.f;
  #pragma unroll
  for (int q = 0; q < 3; q++) { float d = v[q] - mu; s2 += d * d; }
  #pragma unroll
  for (int off = 32; off; off >>= 1) s2 += __shfl_down(s2, off);
  if ((tid & 63) == 0) red[tid >> 6] = s2;
  __syncthreads();
  const float rs = rsqrtf((red[0] + red[1] + red[2] + red[3]) * (1.f / DMODEL) + EPSF);
  unsigned short* xo = xn + (size_t)row * DMODEL;
  #pragma unroll
  for (int q = 0; q < 3; q++) {
    int col = q*256 + tid;
    xo[col] = f2bf((v[q] - mu) * rs * w[col] + b[col]);
  }
}

// ---------------- W[K][N] fp32 -> Wt[N][K] bf16 (tiled transpose) ----------------
__global__ __launch_bounds__(256) void k_wtrans(const float* __restrict__ W,
    unsigned short* __restrict__ Wt, int K, int N)
{
  __shared__ float tile[32][33];
  const int tid = threadIdx.x;
  const int tx = tid & 31, ty = tid >> 5;           // 32 x 8
  const int n0 = blockIdx.x * 32, k0 = blockIdx.y * 32;
  #pragma unroll
  for (int r = 0; r < 4; r++) {
    int k = k0 + ty + 8*r;
    if (k < K && n0 + tx < N) tile[ty + 8*r][tx] = W[(size_t)k * N + n0 + tx];
  }
  __syncthreads();
  #pragma unroll
  for (int r = 0; r < 4; r++) {
    int n = n0 + ty + 8*r, k = k0 + tx;
    if (n < N && k < K) Wt[(size_t)n * K + k] = f2bf(tile[tx][ty + 8*r]);
  }
}

// ---------------- bf16 MFMA GEMM: C[M][N] = A[M][K] @ Bt[N][K]^T ----------------
// epi: 0 plain, 1 sigmoid(C+bias[n]), 2 C+bias[n]+resid[m][n].  Cb!=null -> bf16 out.
__global__ __launch_bounds__(256) void k_gemm(const unsigned short* __restrict__ A,
    const unsigned short* __restrict__ Bt, float* __restrict__ C,
    unsigned short* __restrict__ Cb,
    int M, int N, int K, int epi, const float* __restrict__ bias,
    const float* __restrict__ resid)
{
  __shared__ alignas(16) unsigned short As[128][40];
  __shared__ alignas(16) unsigned short Bs[128][40];
  const int tid = threadIdx.x;
  const int m0 = blockIdx.y * 128, n0 = blockIdx.x * 128;
  const int lane = tid & 63, wv = tid >> 6;
  const int wm = (wv >> 1) * 64, wn = (wv & 1) * 64;
  const int l15 = lane & 15, lq = lane >> 4;
  f32x4 acc[4][4];
  #pragma unroll
  for (int i = 0; i < 4; i++)
    #pragma unroll
    for (int j = 0; j < 4; j++) acc[i][j] = (f32x4){0.f, 0.f, 0.f, 0.f};

  const int rowA = tid >> 2, kqA = (tid & 3) * 8;
  for (int k0 = 0; k0 < K; k0 += 32) {
    __syncthreads();
    #pragma unroll
    for (int it = 0; it < 2; it++) {
      int row = rowA + it * 64;
      int4 va = *(const int4*)(A + (size_t)(m0 + row) * K + k0 + kqA);
      *(int4*)(&As[row][kqA]) = va;
      int nrow = n0 + row;
      int4 vb = make_int4(0, 0, 0, 0);
      if (nrow < N) vb = *(const int4*)(Bt + (size_t)nrow * K + k0 + kqA);
      *(int4*)(&Bs[row][kqA]) = vb;
    }
    __syncthreads();
    short8 a8[4], b8[4];
    #pragma unroll
    for (int mi = 0; mi < 4; mi++) a8[mi] = *(const short8*)(&As[wm + 16*mi + l15][lq * 8]);
    #pragma unroll
    for (int ni = 0; ni < 4; ni++) b8[ni] = *(const short8*)(&Bs[wn + 16*ni + l15][lq * 8]);
    #pragma unroll
    for (int mi = 0; mi < 4; mi++)
      #pragma unroll
      for (int ni = 0; ni < 4; ni++)
        acc[mi][ni] = __builtin_amdgcn_mfma_f32_16x16x32_bf16(a8[mi], b8[ni], acc[mi][ni], 0, 0, 0);
  }
  #pragma unroll
  for (int mi = 0; mi < 4; mi++) {
    #pragma unroll
    for (int r = 0; r < 4; r++) {
      int row = m0 + wm + 16*mi + lq*4 + r;
      #pragma unroll
      for (int ni = 0; ni < 4; ni++) {
        int col = n0 + wn + 16*ni + l15;
        if (col < N) {
          float vv = acc[mi][ni][r];
          if (epi == 1)      vv = sigm(vv + bias[col]);
          else if (epi == 2) vv = vv + bias[col] + resid[(size_t)row * N + col];
          if (Cb) Cb[(size_t)row * N + col] = f2bf(vv);
          else    C [(size_t)row * N + col] = vv;
        }
      }
    }
  }
}

// ---------------- causal conv1d (K=4) + SiLU over xBC cols (bf16 in/out) ---------
__global__ __launch_bounds__(256) void k_conv(const unsigned short* __restrict__ zx,
    const float* __restrict__ cw, const float* __restrict__ cb,
    unsigned short* __restrict__ out)
{
  size_t idx = (size_t)blockIdx.x * 256 + threadIdx.x;   // NTOK*CONVD total
  int c = (int)(idx % CONVD);
  size_t bt = idx / CONVD;
  int t = (int)(bt % SEQ);
  const unsigned short* base = zx + bt * DINPROJ + DINNER + c;
  float acc = cb[c];
  #pragma unroll
  for (int k = 0; k < 4; k++) {
    int tt = t - 3 + k;
    if (tt >= 0) acc += bf2f(base[(ptrdiff_t)(k - 3) * DINPROJ]) * cw[c * 4 + k];
  }
  out[bt * CONVD + c] = f2bf(acc * sigm(acc));
}

// ---------------- SSD pass 1 (MFMA): S[bh,c][n][p] = sum_s (B[s][n]*wv[s]) X[s][p]
__global__ __launch_bounds__(256) void k_chunkstate(const unsigned short* __restrict__ zx,
    const unsigned short* __restrict__ xbcc, const float* __restrict__ dt_bias,
    const float* __restrict__ A_log, float* __restrict__ S, float* __restrict__ CD)
{
  const int c = blockIdx.x, bh = blockIdx.y;
  const int b = bh / NH, h = bh % NH;
  const int tid = threadIdx.x;
  const int lane = tid & 63, w = tid >> 6;
  const int l15 = lane & 15, lq = lane >> 4;
  __shared__ float wv_[64];
  __shared__ alignas(16) unsigned short Bwt[64][LP];  // [n][s]
  __shared__ alignas(16) unsigned short Xt [64][LP];  // [p][s]

  if (tid < 64) {                     // wave 0: dt, prefix-scan of Lc
    int t = c * 64 + tid;
    float xx = bf2f(zx[((size_t)(b * SEQ + t)) * DINPROJ + (DINNER + CONVD) + h]) + dt_bias[h];
    float dt_ = (xx > 15.f) ? xx : log1pf(__expf(xx));
    float Ah = -__expf(A_log[h]);
    float v = dt_ * Ah;
    #pragma unroll
    for (int off = 1; off < 64; off <<= 1) {
      float u = __shfl_up(v, off);
      if (tid >= off) v += u;
    }
    float L63 = __shfl(v, 63);
    wv_[tid] = __expf(L63 - v) * dt_;
    if (tid == 63) CD[bh * 64 + c] = __expf(v);
  }
  unsigned long long braw[4];
  #pragma unroll
  for (int it = 0; it < 4; it++) {
    int i4 = tid + 256 * it;
    int rr = i4 >> 4, q4 = (i4 & 15) * 4;
    size_t rb = ((size_t)(b * SEQ) + c * 64 + rr) * CONVD;
    braw[it] = *(const unsigned long long*)(xbcc + rb + DINNER + q4);
    unsigned short xs[4];
    *(unsigned long long*)xs = *(const unsigned long long*)(xbcc + rb + h * HD + q4);
    Xt[q4+0][rr] = xs[0]; Xt[q4+1][rr] = xs[1]; Xt[q4+2][rr] = xs[2]; Xt[q4+3][rr] = xs[3];
  }
  __syncthreads();
  #pragma unroll
  for (int it = 0; it < 4; it++) {
    int i4 = tid + 256 * it;
    int rr = i4 >> 4, q4 = (i4 & 15) * 4;
    float wsc = wv_[rr];
    unsigned short us[4];
    *(unsigned long long*)us = braw[it];
    Bwt[q4+0][rr] = f2bf(bf2f(us[0]) * wsc);
    Bwt[q4+1][rr] = f2bf(bf2f(us[1]) * wsc);
    Bwt[q4+2][rr] = f2bf(bf2f(us[2]) * wsc);
    Bwt[q4+3][rr] = f2bf(bf2f(us[3]) * wsc);
  }
  __syncthreads();
  const int n0 = 16 * w;
  short8 a0 = *(const short8*)(&Bwt[n0 + l15][lq * 8]);
  short8 a1 = *(const short8*)(&Bwt[n0 + l15][32 + lq * 8]);
  size_t sb = ((size_t)bh * 64 + c) * 4096;
  #pragma unroll
  for (int pt = 0; pt < 4; pt++) {
    f32x4 acc = (f32x4){0.f, 0.f, 0.f, 0.f};
    short8 b0 = *(const short8*)(&Xt[16*pt + l15][lq * 8]);
    short8 b1 = *(const short8*)(&Xt[16*pt + l15][32 + lq * 8]);
    acc = __builtin_amdgcn_mfma_f32_16x16x32_bf16(a0, b0, acc, 0, 0, 0);
    acc = __builtin_amdgcn_mfma_f32_16x16x32_bf16(a1, b1, acc, 0, 0, 0);
    #pragma unroll
    for (int r = 0; r < 4; r++) {
      int n = n0 + 4*lq + r, p = 16*pt + l15;
      S[sb + (size_t)n * 64 + p] = acc[r];
    }
  }
}

// ---------------- SSD pass 2: chunk-level recurrence (in-place S -> G) -----------
__global__ __launch_bounds__(256) void k_chunkrec(float* __restrict__ S,
    const float* __restrict__ CD)
{
  const int bh = blockIdx.x >> 4, part = blockIdx.x & 15;
  const int e = part * 256 + threadIdx.x;
  float g = 0.f;
  size_t base = (size_t)bh * 64 * 4096 + e;
  for (int c = 0; c < 64; c++) {
    size_t ad = base + (size_t)c * 4096;
    float sv = S[ad];
    float pc = CD[bh * 64 + c];
    S[ad] = g;               // slot c now holds G_c (state before chunk c)
    g = pc * g + sv;
  }
}

// ---------------- SSD pass 3 (MFMA): per-chunk outputs (bf16 Y out) --------------
__global__ __launch_bounds__(256) void k_chunkout(const unsigned short* __restrict__ zx,
    const unsigned short* __restrict__ xbcc, const float* __restrict__ S,
    const float* __restrict__ dt_bias, const float* __restrict__ A_log,
    const float* __restrict__ Dp, unsigned short* __restrict__ Y)
{
  const int c = blockIdx.x, bh = blockIdx.y;
  const int b = bh / NH, h = bh % NH;
  const int tid = threadIdx.x;
  const int lane = tid & 63, w = tid >> 6;
  const int l15 = lane & 15, lq = lane >> 4;
  __shared__ float dts[64], Lc[64], ein[64];
  __shared__ alignas(16) unsigned short Cs  [64][LP];  // [i][n]
  __shared__ alignas(16) unsigned short BsPs[64][LP];  // [s][n], then P[i][s]
  __shared__ alignas(16) unsigned short Xt  [64][LP];  // [p][s]
  __shared__ alignas(16) unsigned short Gt  [64][LP];  // [p][n]

  if (tid < 64) {                     // wave 0: dt, prefix-scan of Lc
    int t = c * 64 + tid;
    float xx = bf2f(zx[((size_t)(b * SEQ + t)) * DINPROJ + (DINNER + CONVD) + h]) + dt_bias[h];
    float dt_ = (xx > 15.f) ? xx : log1pf(__expf(xx));
    dts[tid] = dt_;
    float Ah = -__expf(A_log[h]);
    float v = dt_ * Ah;
    #pragma unroll
    for (int off = 1; off < 64; off <<= 1) {
      float u = __shfl_up(v, off);
      if (tid >= off) v += u;
    }
    Lc[tid] = v;
    ein[tid] = __expf(v);
  }
  const size_t gslot = ((size_t)bh * 64 + c) * 4096;
  #pragma unroll
  for (int it = 0; it < 4; it++) {
    int i4 = tid + 256 * it;
    int rr = i4 >> 4, q4 = (i4 & 15) * 4;
    size_t rb = ((size_t)(b * SEQ) + c * 64 + rr) * CONVD;
    *(unsigned long long*)(&Cs[rr][q4])   = *(const unsigned long long*)(xbcc + rb + (DINNER + DSTATE) + q4);
    *(unsigned long long*)(&BsPs[rr][q4]) = *(const unsigned long long*)(xbcc + rb + DINNER + q4);
    unsigned short xs[4];
    *(unsigned long long*)xs = *(const unsigned long long*)(xbcc + rb + h * HD + q4);
    Xt[q4+0][rr] = xs[0]; Xt[q4+1][rr] = xs[1]; Xt[q4+2][rr] = xs[2]; Xt[q4+3][rr] = xs[3];
    float4 vG = *(const float4*)(S + gslot + (size_t)i4 * 4);   // row n=rr, cols q4..q4+3
    Gt[q4+0][rr] = f2bf(vG.x); Gt[q4+1][rr] = f2bf(vG.y);
    Gt[q4+2][rr] = f2bf(vG.z); Gt[q4+3][rr] = f2bf(vG.w);
  }
  __syncthreads();
  // ---- matmul1: G[i][s] = sum_n C[i][n] B[s][n]; apply causal decay mask -> P ----
  const int i0 = 16 * w;
  short8 ac0 = *(const short8*)(&Cs[i0 + l15][lq * 8]);
  short8 ac1 = *(const short8*)(&Cs[i0 + l15][32 + lq * 8]);
  float pp[4][4];
  #pragma unroll
  for (int st = 0; st < 4; st++) {
    f32x4 g = (f32x4){0.f, 0.f, 0.f, 0.f};
    if (st <= w) {                                   // wave-uniform causal skip
      short8 b0 = *(const short8*)(&BsPs[16*st + l15][lq * 8]);
      short8 b1 = *(const short8*)(&BsPs[16*st + l15][32 + lq * 8]);
      g = __builtin_amdgcn_mfma_f32_16x16x32_bf16(ac0, b0, g, 0, 0, 0);
      g = __builtin_amdgcn_mfma_f32_16x16x32_bf16(ac1, b1, g, 0, 0, 0);
    }
    #pragma unroll
    for (int r = 0; r < 4; r++) {
      int i = i0 + 4*lq + r, s = 16*st + l15;
      pp[st][r] = (s <= i) ? g[r] * __expf(Lc[i] - Lc[s]) * dts[s] : 0.f;
    }
  }
  __syncthreads();                                   // all waves done reading Bs
  #pragma unroll
  for (int st = 0; st < 4; st++)
    #pragma unroll
    for (int r = 0; r < 4; r++)
      BsPs[i0 + 4*lq + r][16*st + l15] = f2bf(pp[st][r]);   // P[i][s], s contiguous
  __syncthreads();
  // ---- matmul2+3: Y[i][p] = P@X + ein[i]*(C@G) + D*x ----
  short8 ap0 = *(const short8*)(&BsPs[i0 + l15][lq * 8]);
  short8 ap1 = *(const short8*)(&BsPs[i0 + l15][32 + lq * 8]);
  const float Dh = Dp[h];
  #pragma unroll
  for (int pt = 0; pt < 4; pt++) {
    const int p0 = 16 * pt;
    f32x4 y1 = (f32x4){0.f, 0.f, 0.f, 0.f};
    f32x4 y2 = (f32x4){0.f, 0.f, 0.f, 0.f};
    short8 bx0 = *(const short8*)(&Xt[p0 + l15][lq * 8]);
    y1 = __builtin_amdgcn_mfma_f32_16x16x32_bf16(ap0, bx0, y1, 0, 0, 0);
    if (w >= 2) {                                    // P rows of wave w have k < 16(w+1)
      short8 bx1 = *(const short8*)(&Xt[p0 + l15][32 + lq * 8]);
      y1 = __builtin_amdgcn_mfma_f32_16x16x32_bf16(ap1, bx1, y1, 0, 0, 0);
    }
    short8 bg0 = *(const short8*)(&Gt[p0 + l15][lq * 8]);
    short8 bg1 = *(const short8*)(&Gt[p0 + l15][32 + lq * 8]);
    y2 = __builtin_amdgcn_mfma_f32_16x16x32_bf16(ac0, bg0, y2, 0, 0, 0);
    y2 = __builtin_amdgcn_mfma_f32_16x16x32_bf16(ac1, bg1, y2, 0, 0, 0);
    #pragma unroll
    for (int r = 0; r < 4; r++) {
      int i = i0 + 4*lq + r, p = p0 + l15;
      float xv = bf2f(Xt[p][i]);
      float o = y1[r] + ein[i] * y2[r] + Dh * xv;
      Y[((size_t)(b * SEQ) + c * 64 + i) * DINNER + h * HD + p] = f2bf(o);
    }
  }
}

// ---------------- y*silu(z), RMSNorm -> bf16 -------------------------------------
__global__ __launch_bounds__(256) void k_fuse(const unsigned short* __restrict__ Y,
    const unsigned short* __restrict__ ZX, const float* __restrict__ rw,
    unsigned short* __restrict__ YN)
{
  __shared__ float red[4];
  const int row = blockIdx.x, tid = threadIdx.x;
  const unsigned short* yr = Y + (size_t)row * DINNER;
  const unsigned short* zr = ZX + (size_t)row * DINPROJ;
  float v[6]; float s2 = 0.f;
  #pragma unroll
  for (int q = 0; q < 6; q++) {
    int col = q * 256 + tid;
    float z = bf2f(zr[col]);
    float yv = bf2f(yr[col]) * (z * sigm(z));
    v[q] = yv; s2 += yv * yv;
  }
  #pragma unroll
  for (int off = 32; off; off >>= 1) s2 += __shfl_down(s2, off);
  if ((tid & 63) == 0) red[tid >> 6] = s2;
  __syncthreads();
  const float rs = rsqrtf((red[0] + red[1] + red[2] + red[3]) * (1.f / DINNER) + EPSF);
  unsigned short* yo = YN + (size_t)row * DINNER;
  #pragma unroll
  for (int q = 0; q < 6; q++) {
    int col = q * 256 + tid;
    yo[col] = f2bf(v[q] * rs * rw[col]);
  }
}

// ---------------- yg = bf16(yproj * gate) ----------------------------------------
__global__ __launch_bounds__(256) void k_gatemul(const float* __restrict__ YP,
    const float* __restrict__ G, unsigned short* __restrict__ YG)
{
  size_t idx = (size_t)blockIdx.x * 256 + threadIdx.x;
  YG[idx] = f2bf(YP[idx] * G[idx]);
}

// ---------------- launch ----------------------------------------------------------
extern "C" void kernel_launch(void* const* d_in, const int* in_sizes, int n_in,
                              void* d_out, int out_size, void* d_ws, size_t ws_size,
                              hipStream_t stream)
{
  const float* x         = (const float*)d_in[0];
  const float* ln_w      = (const float*)d_in[1];
  const float* ln_b      = (const float*)d_in[2];
  const float* in_proj_w = (const float*)d_in[3];
  const float* conv_w    = (const float*)d_in[4];
  const float* conv_b    = (const float*)d_in[5];
  const float* dt_bias   = (const float*)d_in[6];
  const float* A_log     = (const float*)d_in[7];
  const float* D_param   = (const float*)d_in[8];
  const float* rms_w     = (const float*)d_in[9];
  const float* out_proj_w= (const float*)d_in[10];
  const float* gate_w    = (const float*)d_in[11];
  const float* gate_b    = (const float*)d_in[12];
  const float* out_w     = (const float*)d_in[13];
  const float* out_b     = (const float*)d_in[14];
  float* out = (float*)d_out;
  char* ws = (char*)d_ws;

  // ---- workspace layout (bytes). peak = 177,848,320 B (~170 MB) ----
  const size_t WS_NEEDED = 177848320ull;
  if (ws_size < WS_NEEDED) return;

  unsigned short* XN    = (unsigned short*)(ws + 0);
  unsigned short* WIT   = (unsigned short*)(ws + 12582912);
  unsigned short* WGT   = (unsigned short*)(ws + 17534976);
  unsigned short* WOPT  = (unsigned short*)(ws + 18714624);
  unsigned short* WOT   = (unsigned short*)(ws + 21073920);
  unsigned short* ZXb   = (unsigned short*)(ws + 22253568);   // 8192x3224 bf16
  unsigned short* XBCCb = (unsigned short*)(ws + 75075584);   // 8192x1664 bf16
  float*          SG    = (float*)(ws + 102338560);           // 3072x4096 f32
  float*          CD    = (float*)(ws + 152670208);           // 3072 f32
  unsigned short* Yb    = (unsigned short*)(ws + 152682496);  // 8192x1536 bf16
  // overlays:
  unsigned short* YN    = (unsigned short*)(ws + 102338560);  // in SG region (dead after chunkout)
  float*          GATE  = (float*)(ws + 22253568);            // in ZXb region (dead after fuse)
  float*          YPROJ = (float*)(ws + 47419392);            // in ZXb region
  unsigned short* YG    = (unsigned short*)(ws + 75075584);   // in XBCCb region (dead after chunkout)

  // 1) weight converts (bf16, transposed for TN GEMM)
  k_wtrans<<<dim3(101, 24), 256, 0, stream>>>(in_proj_w,  WIT,  768,  3224);
  k_wtrans<<<dim3(24, 24),  256, 0, stream>>>(gate_w,     WGT,  768,  768);
  k_wtrans<<<dim3(24, 48),  256, 0, stream>>>(out_proj_w, WOPT, 1536, 768);
  k_wtrans<<<dim3(24, 24),  256, 0, stream>>>(out_w,      WOT,  768,  768);
  // 2) layernorm
  k_ln<<<NTOK, 256, 0, stream>>>(x, ln_w, ln_b, XN);
  // 3) in_proj GEMM -> zxbcdt (bf16)
  k_gemm<<<dim3(26, 64), 256, 0, stream>>>(XN, WIT, nullptr, ZXb, NTOK, DINPROJ, DMODEL, 0, nullptr, nullptr);
  // 4) causal conv + silu (bf16 -> bf16)
  k_conv<<<(NTOK * CONVD) / 256, 256, 0, stream>>>(ZXb, conv_w, conv_b, XBCCb);
  // 5-7) SSD scan
  k_chunkstate<<<dim3(NCHUNK, BSZ * NH), 256, 0, stream>>>(ZXb, XBCCb, dt_bias, A_log, SG, CD);
  k_chunkrec<<<BSZ * NH * 16, 256, 0, stream>>>(SG, CD);
  k_chunkout<<<dim3(NCHUNK, BSZ * NH), 256, 0, stream>>>(ZXb, XBCCb, SG, dt_bias, A_log, D_param, Yb);
  // 8) y*silu(z) + RMSNorm -> bf16 (YN lands in dead SG region)
  k_fuse<<<NTOK, 256, 0, stream>>>(Yb, ZXb, rms_w, YN);
  // 9) gate GEMM (sigmoid epilogue) -> dead ZXb region
  k_gemm<<<dim3(6, 64), 256, 0, stream>>>(XN, WGT, GATE, nullptr, NTOK, DMODEL, DMODEL, 1, gate_b, nullptr);
  // 10) out_proj GEMM
  k_gemm<<<dim3(6, 64), 256, 0, stream>>>(YN, WOPT, YPROJ, nullptr, NTOK, DMODEL, DINNER, 0, nullptr, nullptr);
  // 11) gate multiply -> bf16
  k_gatemul<<<(NTOK * DMODEL) / 256, 256, 0, stream>>>(YPROJ, GATE, YG);
  // 12) final GEMM + bias + residual -> d_out
  k_gemm<<<dim3(6, 64), 256, 0, stream>>>(YG, WOT, out, nullptr, NTOK, DMODEL, DMODEL, 2, out_b, x);
}

// Round 4
// 497.910 us; speedup vs baseline: 1.2237x; 1.0571x over previous
//
#include <hip/hip_runtime.h>
#include <hip/hip_bf16.h>
#include <cstddef>

// ---------------- problem constants ----------------
#define DMODEL  768
#define DINNER  1536
#define DSTATE  64
#define NH      24
#define HD      64
#define CONVD   1664      // DINNER + 2*DSTATE
#define DINPROJ 3224      // 2*DINNER + 2*DSTATE + NH
#define SEQ     4096
#define BSZ     2
#define NTOK    8192      // BSZ*SEQ
#define NCHUNK  64        // SEQ/64
#define EPSF    1e-5f
#define LP      72        // LDS pitch (shorts) for SSD kernels

typedef __attribute__((ext_vector_type(8))) short  short8;
typedef __attribute__((ext_vector_type(4))) float  f32x4;

// ---------------- helpers ----------------
__device__ __forceinline__ unsigned short f2bf(float f) {
  union { float f; unsigned int u; } v; v.f = f;
  unsigned int r = v.u + 0x7fffu + ((v.u >> 16) & 1u);   // RNE
  return (unsigned short)(r >> 16);
}
__device__ __forceinline__ float bf2f(unsigned short u) {
  union { unsigned int i; float f; } v; v.i = ((unsigned int)u) << 16; return v.f;
}
__device__ __forceinline__ float sigm(float x) { return 1.f / (1.f + __expf(-x)); }

// async 16B global -> LDS (lane i of the wave lands at ldsbase + i*16)
__device__ __forceinline__ void gld16(const unsigned short* g, unsigned short* l) {
  __builtin_amdgcn_global_load_lds(
      (const __attribute__((address_space(1))) unsigned int*)g,
      (__attribute__((address_space(3))) unsigned int*)l, 16, 0, 0);
}

// ---------------- LayerNorm -> bf16 ----------------
__global__ __launch_bounds__(256) void k_ln(const float* __restrict__ x,
    const float* __restrict__ w, const float* __restrict__ b,
    unsigned short* __restrict__ xn)
{
  __shared__ float red[4];
  const int row = blockIdx.x, tid = threadIdx.x;
  const float* xr = x + (size_t)row * DMODEL;
  float v[3]; float s = 0.f;
  #pragma unroll
  for (int q = 0; q < 3; q++) { v[q] = xr[q*256 + tid]; s += v[q]; }
  #pragma unroll
  for (int off = 32; off; off >>= 1) s += __shfl_down(s, off);
  if ((tid & 63) == 0) red[tid >> 6] = s;
  __syncthreads();
  const float mu = (red[0] + red[1] + red[2] + red[3]) * (1.f / DMODEL);
  __syncthreads();
  float s2 = 0.f;
  #pragma unroll
  for (int q = 0; q < 3; q++) { float d = v[q] - mu; s2 += d * d; }
  #pragma unroll
  for (int off = 32; off; off >>= 1) s2 += __shfl_down(s2, off);
  if ((tid & 63) == 0) red[tid >> 6] = s2;
  __syncthreads();
  const float rs = rsqrtf((red[0] + red[1] + red[2] + red[3]) * (1.f / DMODEL) + EPSF);
  unsigned short* xo = xn + (size_t)row * DMODEL;
  #pragma unroll
  for (int q = 0; q < 3; q++) {
    int col = q*256 + tid;
    xo[col] = f2bf((v[q] - mu) * rs * w[col] + b[col]);
  }
}

// ---------------- W[K][N] fp32 -> Wt[N][K] bf16 (tiled transpose) ----------------
__global__ __launch_bounds__(256) void k_wtrans(const float* __restrict__ W,
    unsigned short* __restrict__ Wt, int K, int N)
{
  __shared__ float tile[32][33];
  const int tid = threadIdx.x;
  const int tx = tid & 31, ty = tid >> 5;           // 32 x 8
  const int n0 = blockIdx.x * 32, k0 = blockIdx.y * 32;
  #pragma unroll
  for (int r = 0; r < 4; r++) {
    int k = k0 + ty + 8*r;
    if (k < K && n0 + tx < N) tile[ty + 8*r][tx] = W[(size_t)k * N + n0 + tx];
  }
  __syncthreads();
  #pragma unroll
  for (int r = 0; r < 4; r++) {
    int n = n0 + ty + 8*r, k = k0 + tx;
    if (n < N && k < K) Wt[(size_t)n * K + k] = f2bf(tile[tx][ty + 8*r]);
  }
}

// ---------------- bf16 MFMA GEMM: C[M][N] = A[M][K] @ Bt[N][K]^T ----------------
// global_load_lds staging (16B), swizzled LDS layout: granule j of row r holds
// k-chunk q = j ^ ((r>>2)&3)  -> fragment ds_read_b128 phases are bank-balanced.
// epi: 0 plain, 1 sigmoid(C+bias[n]), 2 C+bias[n]+resid[m][n].  Cb!=null -> bf16 out.
__global__ __launch_bounds__(256) void k_gemm(const unsigned short* __restrict__ A,
    const unsigned short* __restrict__ Bt, float* __restrict__ C,
    unsigned short* __restrict__ Cb,
    int M, int N, int K, int epi, const float* __restrict__ bias,
    const float* __restrict__ resid)
{
  __shared__ alignas(16) unsigned short As[128 * 32];
  __shared__ alignas(16) unsigned short Bs[128 * 32];
  const int tid = threadIdx.x;
  const int m0 = blockIdx.y * 128, n0 = blockIdx.x * 128;
  const int lane = tid & 63, w = tid >> 6;
  const int wm = (w >> 1) * 64, wn = (w & 1) * 64;
  const int l15 = lane & 15, lq = lane >> 4;
  const int sw = l15 >> 2;                 // fragment-read swizzle
  f32x4 acc[4][4];
  #pragma unroll
  for (int i = 0; i < 4; i++)
    #pragma unroll
    for (int j = 0; j < 4; j++) acc[i][j] = (f32x4){0.f, 0.f, 0.f, 0.f};

  // staging geometry: 2 rounds x 4 waves x 64 lanes = 512 granules (128 rows x 4)
  int rowg[2], qg[2];
  #pragma unroll
  for (int r = 0; r < 2; r++) {
    int gi = (r * 4 + w) * 64 + lane;
    rowg[r] = gi >> 2;
    qg[r] = (gi & 3) ^ ((rowg[r] >> 2) & 3);
  }

  for (int k0 = 0; k0 < K; k0 += 32) {
    __syncthreads();
    #pragma unroll
    for (int r = 0; r < 2; r++) {
      gld16(A + (size_t)(m0 + rowg[r]) * K + k0 + qg[r] * 8, &As[(r * 4 + w) * 512]);
      int nr = n0 + rowg[r]; if (nr >= N) nr = N - 1;   // clamp; cols >= N masked in epilogue
      gld16(Bt + (size_t)nr * K + k0 + qg[r] * 8, &Bs[(r * 4 + w) * 512]);
    }
    __syncthreads();
    short8 a8[4], b8[4];
    #pragma unroll
    for (int mi = 0; mi < 4; mi++)
      a8[mi] = *(const short8*)(&As[(wm + 16 * mi + l15) * 32 + (lq ^ sw) * 8]);
    #pragma unroll
    for (int ni = 0; ni < 4; ni++)
      b8[ni] = *(const short8*)(&Bs[(wn + 16 * ni + l15) * 32 + (lq ^ sw) * 8]);
    #pragma unroll
    for (int mi = 0; mi < 4; mi++)
      #pragma unroll
      for (int ni = 0; ni < 4; ni++)
        acc[mi][ni] = __builtin_amdgcn_mfma_f32_16x16x32_bf16(a8[mi], b8[ni], acc[mi][ni], 0, 0, 0);
  }
  #pragma unroll
  for (int mi = 0; mi < 4; mi++) {
    #pragma unroll
    for (int r = 0; r < 4; r++) {
      int row = m0 + wm + 16*mi + lq*4 + r;
      #pragma unroll
      for (int ni = 0; ni < 4; ni++) {
        int col = n0 + wn + 16*ni + l15;
        if (col < N) {
          float vv = acc[mi][ni][r];
          if (epi == 1)      vv = sigm(vv + bias[col]);
          else if (epi == 2) vv = vv + bias[col] + resid[(size_t)row * N + col];
          if (Cb) Cb[(size_t)row * N + col] = f2bf(vv);
          else    C [(size_t)row * N + col] = vv;
        }
      }
    }
  }
}

// ---------------- causal conv1d (K=4) + SiLU over xBC cols (bf16 in/out) ---------
__global__ __launch_bounds__(256) void k_conv(const unsigned short* __restrict__ zx,
    const float* __restrict__ cw, const float* __restrict__ cb,
    unsigned short* __restrict__ out)
{
  size_t idx = (size_t)blockIdx.x * 256 + threadIdx.x;   // NTOK*CONVD total
  int c = (int)(idx % CONVD);
  size_t bt = idx / CONVD;
  int t = (int)(bt % SEQ);
  const unsigned short* base = zx + bt * DINPROJ + DINNER + c;
  float acc = cb[c];
  #pragma unroll
  for (int k = 0; k < 4; k++) {
    int tt = t - 3 + k;
    if (tt >= 0) acc += bf2f(base[(ptrdiff_t)(k - 3) * DINPROJ]) * cw[c * 4 + k];
  }
  out[bt * CONVD + c] = f2bf(acc * sigm(acc));
}

// ---------------- SSD pass 1 (MFMA): S[bh,c][n][p] = sum_s (B[s][n]*wv[s]) X[s][p]
__global__ __launch_bounds__(256) void k_chunkstate(const unsigned short* __restrict__ zx,
    const unsigned short* __restrict__ xbcc, const float* __restrict__ dt_bias,
    const float* __restrict__ A_log, float* __restrict__ S, float* __restrict__ CD)
{
  const int c = blockIdx.x, bh = blockIdx.y;
  const int b = bh / NH, h = bh % NH;
  const int tid = threadIdx.x;
  const int lane = tid & 63, w = tid >> 6;
  const int l15 = lane & 15, lq = lane >> 4;
  __shared__ float wv_[64];
  __shared__ alignas(16) unsigned short Bwt[64][LP];  // [n][s]
  __shared__ alignas(16) unsigned short Xt [64][LP];  // [p][s]

  if (tid < 64) {                     // wave 0: dt, prefix-scan of Lc
    int t = c * 64 + tid;
    float xx = bf2f(zx[((size_t)(b * SEQ + t)) * DINPROJ + (DINNER + CONVD) + h]) + dt_bias[h];
    float dt_ = (xx > 15.f) ? xx : log1pf(__expf(xx));
    float Ah = -__expf(A_log[h]);
    float v = dt_ * Ah;
    #pragma unroll
    for (int off = 1; off < 64; off <<= 1) {
      float u = __shfl_up(v, off);
      if (tid >= off) v += u;
    }
    float L63 = __shfl(v, 63);
    wv_[tid] = __expf(L63 - v) * dt_;
    if (tid == 63) CD[bh * 64 + c] = __expf(v);
  }
  unsigned long long braw[4];
  #pragma unroll
  for (int it = 0; it < 4; it++) {
    int i4 = tid + 256 * it;
    int rr = i4 >> 4, q4 = (i4 & 15) * 4;
    size_t rb = ((size_t)(b * SEQ) + c * 64 + rr) * CONVD;
    braw[it] = *(const unsigned long long*)(xbcc + rb + DINNER + q4);
    unsigned short xs[4];
    *(unsigned long long*)xs = *(const unsigned long long*)(xbcc + rb + h * HD + q4);
    Xt[q4+0][rr] = xs[0]; Xt[q4+1][rr] = xs[1]; Xt[q4+2][rr] = xs[2]; Xt[q4+3][rr] = xs[3];
  }
  __syncthreads();
  #pragma unroll
  for (int it = 0; it < 4; it++) {
    int i4 = tid + 256 * it;
    int rr = i4 >> 4, q4 = (i4 & 15) * 4;
    float wsc = wv_[rr];
    unsigned short us[4];
    *(unsigned long long*)us = braw[it];
    Bwt[q4+0][rr] = f2bf(bf2f(us[0]) * wsc);
    Bwt[q4+1][rr] = f2bf(bf2f(us[1]) * wsc);
    Bwt[q4+2][rr] = f2bf(bf2f(us[2]) * wsc);
    Bwt[q4+3][rr] = f2bf(bf2f(us[3]) * wsc);
  }
  __syncthreads();
  const int n0 = 16 * w;
  short8 a0 = *(const short8*)(&Bwt[n0 + l15][lq * 8]);
  short8 a1 = *(const short8*)(&Bwt[n0 + l15][32 + lq * 8]);
  size_t sb = ((size_t)bh * 64 + c) * 4096;
  #pragma unroll
  for (int pt = 0; pt < 4; pt++) {
    f32x4 acc = (f32x4){0.f, 0.f, 0.f, 0.f};
    short8 b0 = *(const short8*)(&Xt[16*pt + l15][lq * 8]);
    short8 b1 = *(const short8*)(&Xt[16*pt + l15][32 + lq * 8]);
    acc = __builtin_amdgcn_mfma_f32_16x16x32_bf16(a0, b0, acc, 0, 0, 0);
    acc = __builtin_amdgcn_mfma_f32_16x16x32_bf16(a1, b1, acc, 0, 0, 0);
    #pragma unroll
    for (int r = 0; r < 4; r++) {
      int n = n0 + 4*lq + r, p = 16*pt + l15;
      S[sb + (size_t)n * 64 + p] = acc[r];
    }
  }
}

// ---------------- SSD pass 2: chunk-level recurrence (in-place S -> G) -----------
__global__ __launch_bounds__(256) void k_chunkrec(float* __restrict__ S,
    const float* __restrict__ CD)
{
  const int bh = blockIdx.x >> 4, part = blockIdx.x & 15;
  const int e = part * 256 + threadIdx.x;
  float g = 0.f;
  size_t base = (size_t)bh * 64 * 4096 + e;
  for (int c = 0; c < 64; c++) {
    size_t ad = base + (size_t)c * 4096;
    float sv = S[ad];
    float pc = CD[bh * 64 + c];
    S[ad] = g;               // slot c now holds G_c (state before chunk c)
    g = pc * g + sv;
  }
}

// ---------------- SSD pass 3 (MFMA): per-chunk outputs (bf16 Y out) --------------
__global__ __launch_bounds__(256) void k_chunkout(const unsigned short* __restrict__ zx,
    const unsigned short* __restrict__ xbcc, const float* __restrict__ S,
    const float* __restrict__ dt_bias, const float* __restrict__ A_log,
    const float* __restrict__ Dp, unsigned short* __restrict__ Y)
{
  const int c = blockIdx.x, bh = blockIdx.y;
  const int b = bh / NH, h = bh % NH;
  const int tid = threadIdx.x;
  const int lane = tid & 63, w = tid >> 6;
  const int l15 = lane & 15, lq = lane >> 4;
  __shared__ float dts[64], Lc[64], ein[64];
  __shared__ alignas(16) unsigned short Cs  [64][LP];  // [i][n]
  __shared__ alignas(16) unsigned short BsPs[64][LP];  // [s][n], then P[i][s]
  __shared__ alignas(16) unsigned short Xt  [64][LP];  // [p][s]
  __shared__ alignas(16) unsigned short Gt  [64][LP];  // [p][n]

  if (tid < 64) {                     // wave 0: dt, prefix-scan of Lc
    int t = c * 64 + tid;
    float xx = bf2f(zx[((size_t)(b * SEQ + t)) * DINPROJ + (DINNER + CONVD) + h]) + dt_bias[h];
    float dt_ = (xx > 15.f) ? xx : log1pf(__expf(xx));
    dts[tid] = dt_;
    float Ah = -__expf(A_log[h]);
    float v = dt_ * Ah;
    #pragma unroll
    for (int off = 1; off < 64; off <<= 1) {
      float u = __shfl_up(v, off);
      if (tid >= off) v += u;
    }
    Lc[tid] = v;
    ein[tid] = __expf(v);
  }
  const size_t gslot = ((size_t)bh * 64 + c) * 4096;
  #pragma unroll
  for (int it = 0; it < 4; it++) {
    int i4 = tid + 256 * it;
    int rr = i4 >> 4, q4 = (i4 & 15) * 4;
    size_t rb = ((size_t)(b * SEQ) + c * 64 + rr) * CONVD;
    *(unsigned long long*)(&Cs[rr][q4])   = *(const unsigned long long*)(xbcc + rb + (DINNER + DSTATE) + q4);
    *(unsigned long long*)(&BsPs[rr][q4]) = *(const unsigned long long*)(xbcc + rb + DINNER + q4);
    unsigned short xs[4];
    *(unsigned long long*)xs = *(const unsigned long long*)(xbcc + rb + h * HD + q4);
    Xt[q4+0][rr] = xs[0]; Xt[q4+1][rr] = xs[1]; Xt[q4+2][rr] = xs[2]; Xt[q4+3][rr] = xs[3];
    float4 vG = *(const float4*)(S + gslot + (size_t)i4 * 4);   // row n=rr, cols q4..q4+3
    Gt[q4+0][rr] = f2bf(vG.x); Gt[q4+1][rr] = f2bf(vG.y);
    Gt[q4+2][rr] = f2bf(vG.z); Gt[q4+3][rr] = f2bf(vG.w);
  }
  __syncthreads();
  // ---- matmul1: G[i][s] = sum_n C[i][n] B[s][n]; apply causal decay mask -> P ----
  const int i0 = 16 * w;
  short8 ac0 = *(const short8*)(&Cs[i0 + l15][lq * 8]);
  short8 ac1 = *(const short8*)(&Cs[i0 + l15][32 + lq * 8]);
  float pp[4][4];
  #pragma unroll
  for (int st = 0; st < 4; st++) {
    f32x4 g = (f32x4){0.f, 0.f, 0.f, 0.f};
    if (st <= w) {                                   // wave-uniform causal skip
      short8 b0 = *(const short8*)(&BsPs[16*st + l15][lq * 8]);
      short8 b1 = *(const short8*)(&BsPs[16*st + l15][32 + lq * 8]);
      g = __builtin_amdgcn_mfma_f32_16x16x32_bf16(ac0, b0, g, 0, 0, 0);
      g = __builtin_amdgcn_mfma_f32_16x16x32_bf16(ac1, b1, g, 0, 0, 0);
    }
    #pragma unroll
    for (int r = 0; r < 4; r++) {
      int i = i0 + 4*lq + r, s = 16*st + l15;
      pp[st][r] = (s <= i) ? g[r] * __expf(Lc[i] - Lc[s]) * dts[s] : 0.f;
    }
  }
  __syncthreads();                                   // all waves done reading Bs
  #pragma unroll
  for (int st = 0; st < 4; st++)
    #pragma unroll
    for (int r = 0; r < 4; r++)
      BsPs[i0 + 4*lq + r][16*st + l15] = f2bf(pp[st][r]);   // P[i][s], s contiguous
  __syncthreads();
  // ---- matmul2+3: Y[i][p] = P@X + ein[i]*(C@G) + D*x ----
  short8 ap0 = *(const short8*)(&BsPs[i0 + l15][lq * 8]);
  short8 ap1 = *(const short8*)(&BsPs[i0 + l15][32 + lq * 8]);
  const float Dh = Dp[h];
  #pragma unroll
  for (int pt = 0; pt < 4; pt++) {
    const int p0 = 16 * pt;
    f32x4 y1 = (f32x4){0.f, 0.f, 0.f, 0.f};
    f32x4 y2 = (f32x4){0.f, 0.f, 0.f, 0.f};
    short8 bx0 = *(const short8*)(&Xt[p0 + l15][lq * 8]);
    y1 = __builtin_amdgcn_mfma_f32_16x16x32_bf16(ap0, bx0, y1, 0, 0, 0);
    if (w >= 2) {                                    // P rows of wave w have k < 16(w+1)
      short8 bx1 = *(const short8*)(&Xt[p0 + l15][32 + lq * 8]);
      y1 = __builtin_amdgcn_mfma_f32_16x16x32_bf16(ap1, bx1, y1, 0, 0, 0);
    }
    short8 bg0 = *(const short8*)(&Gt[p0 + l15][lq * 8]);
    short8 bg1 = *(const short8*)(&Gt[p0 + l15][32 + lq * 8]);
    y2 = __builtin_amdgcn_mfma_f32_16x16x32_bf16(ac0, bg0, y2, 0, 0, 0);
    y2 = __builtin_amdgcn_mfma_f32_16x16x32_bf16(ac1, bg1, y2, 0, 0, 0);
    #pragma unroll
    for (int r = 0; r < 4; r++) {
      int i = i0 + 4*lq + r, p = p0 + l15;
      float xv = bf2f(Xt[p][i]);
      float o = y1[r] + ein[i] * y2[r] + Dh * xv;
      Y[((size_t)(b * SEQ) + c * 64 + i) * DINNER + h * HD + p] = f2bf(o);
    }
  }
}

// ---------------- y*silu(z), RMSNorm -> bf16 -------------------------------------
__global__ __launch_bounds__(256) void k_fuse(const unsigned short* __restrict__ Y,
    const unsigned short* __restrict__ ZX, const float* __restrict__ rw,
    unsigned short* __restrict__ YN)
{
  __shared__ float red[4];
  const int row = blockIdx.x, tid = threadIdx.x;
  const unsigned short* yr = Y + (size_t)row * DINNER;
  const unsigned short* zr = ZX + (size_t)row * DINPROJ;
  float v[6]; float s2 = 0.f;
  #pragma unroll
  for (int q = 0; q < 6; q++) {
    int col = q * 256 + tid;
    float z = bf2f(zr[col]);
    float yv = bf2f(yr[col]) * (z * sigm(z));
    v[q] = yv; s2 += yv * yv;
  }
  #pragma unroll
  for (int off = 32; off; off >>= 1) s2 += __shfl_down(s2, off);
  if ((tid & 63) == 0) red[tid >> 6] = s2;
  __syncthreads();
  const float rs = rsqrtf((red[0] + red[1] + red[2] + red[3]) * (1.f / DINNER) + EPSF);
  unsigned short* yo = YN + (size_t)row * DINNER;
  #pragma unroll
  for (int q = 0; q < 6; q++) {
    int col = q * 256 + tid;
    yo[col] = f2bf(v[q] * rs * rw[col]);
  }
}

// ---------------- yg = bf16(yproj * gate) ----------------------------------------
__global__ __launch_bounds__(256) void k_gatemul(const float* __restrict__ YP,
    const float* __restrict__ G, unsigned short* __restrict__ YG)
{
  size_t idx = (size_t)blockIdx.x * 256 + threadIdx.x;
  YG[idx] = f2bf(YP[idx] * G[idx]);
}

// ---------------- launch ----------------------------------------------------------
extern "C" void kernel_launch(void* const* d_in, const int* in_sizes, int n_in,
                              void* d_out, int out_size, void* d_ws, size_t ws_size,
                              hipStream_t stream)
{
  const float* x         = (const float*)d_in[0];
  const float* ln_w      = (const float*)d_in[1];
  const float* ln_b      = (const float*)d_in[2];
  const float* in_proj_w = (const float*)d_in[3];
  const float* conv_w    = (const float*)d_in[4];
  const float* conv_b    = (const float*)d_in[5];
  const float* dt_bias   = (const float*)d_in[6];
  const float* A_log     = (const float*)d_in[7];
  const float* D_param   = (const float*)d_in[8];
  const float* rms_w     = (const float*)d_in[9];
  const float* out_proj_w= (const float*)d_in[10];
  const float* gate_w    = (const float*)d_in[11];
  const float* gate_b    = (const float*)d_in[12];
  const float* out_w     = (const float*)d_in[13];
  const float* out_b     = (const float*)d_in[14];
  float* out = (float*)d_out;
  char* ws = (char*)d_ws;

  // ---- workspace layout (bytes). peak = 177,848,320 B (~170 MB) ----
  const size_t WS_NEEDED = 177848320ull;
  if (ws_size < WS_NEEDED) return;

  unsigned short* XN    = (unsigned short*)(ws + 0);
  unsigned short* WIT   = (unsigned short*)(ws + 12582912);
  unsigned short* WGT   = (unsigned short*)(ws + 17534976);
  unsigned short* WOPT  = (unsigned short*)(ws + 18714624);
  unsigned short* WOT   = (unsigned short*)(ws + 21073920);
  unsigned short* ZXb   = (unsigned short*)(ws + 22253568);   // 8192x3224 bf16
  unsigned short* XBCCb = (unsigned short*)(ws + 75075584);   // 8192x1664 bf16
  float*          SG    = (float*)(ws + 102338560);           // 3072x4096 f32
  float*          CD    = (float*)(ws + 152670208);           // 3072 f32
  unsigned short* Yb    = (unsigned short*)(ws + 152682496);  // 8192x1536 bf16
  // overlays:
  unsigned short* YN    = (unsigned short*)(ws + 102338560);  // in SG region (dead after chunkout)
  float*          GATE  = (float*)(ws + 22253568);            // in ZXb region (dead after fuse)
  float*          YPROJ = (float*)(ws + 47419392);            // in ZXb region
  unsigned short* YG    = (unsigned short*)(ws + 75075584);   // in XBCCb region (dead after chunkout)

  // 1) weight converts (bf16, transposed for TN GEMM)
  k_wtrans<<<dim3(101, 24), 256, 0, stream>>>(in_proj_w,  WIT,  768,  3224);
  k_wtrans<<<dim3(24, 24),  256, 0, stream>>>(gate_w,     WGT,  768,  768);
  k_wtrans<<<dim3(24, 48),  256, 0, stream>>>(out_proj_w, WOPT, 1536, 768);
  k_wtrans<<<dim3(24, 24),  256, 0, stream>>>(out_w,      WOT,  768,  768);
  // 2) layernorm
  k_ln<<<NTOK, 256, 0, stream>>>(x, ln_w, ln_b, XN);
  // 3) in_proj GEMM -> zxbcdt (bf16)
  k_gemm<<<dim3(26, 64), 256, 0, stream>>>(XN, WIT, nullptr, ZXb, NTOK, DINPROJ, DMODEL, 0, nullptr, nullptr);
  // 4) causal conv + silu (bf16 -> bf16)
  k_conv<<<(NTOK * CONVD) / 256, 256, 0, stream>>>(ZXb, conv_w, conv_b, XBCCb);
  // 5-7) SSD scan
  k_chunkstate<<<dim3(NCHUNK, BSZ * NH), 256, 0, stream>>>(ZXb, XBCCb, dt_bias, A_log, SG, CD);
  k_chunkrec<<<BSZ * NH * 16, 256, 0, stream>>>(SG, CD);
  k_chunkout<<<dim3(NCHUNK, BSZ * NH), 256, 0, stream>>>(ZXb, XBCCb, SG, dt_bias, A_log, D_param, Yb);
  // 8) y*silu(z) + RMSNorm -> bf16 (YN lands in dead SG region)
  k_fuse<<<NTOK, 256, 0, stream>>>(Yb, ZXb, rms_w, YN);
  // 9) gate GEMM (sigmoid epilogue) -> dead ZXb region
  k_gemm<<<dim3(6, 64), 256, 0, stream>>>(XN, WGT, GATE, nullptr, NTOK, DMODEL, DMODEL, 1, gate_b, nullptr);
  // 10) out_proj GEMM
  k_gemm<<<dim3(6, 64), 256, 0, stream>>>(YN, WOPT, YPROJ, nullptr, NTOK, DMODEL, DINNER, 0, nullptr, nullptr);
  // 11) gate multiply -> bf16
  k_gatemul<<<(NTOK * DMODEL) / 256, 256, 0, stream>>>(YPROJ, GATE, YG);
  // 12) final GEMM + bias + residual -> d_out
  k_gemm<<<dim3(6, 64), 256, 0, stream>>>(YG, WOT, out, nullptr, NTOK, DMODEL, DMODEL, 2, out_b, x);
}

// Round 5
// 472.714 us; speedup vs baseline: 1.2889x; 1.0533x over previous
//
#include <hip/hip_runtime.h>
#include <hip/hip_bf16.h>
#include <cstddef>

// ---------------- problem constants ----------------
#define DMODEL  768
#define DINNER  1536
#define DSTATE  64
#define NH      24
#define HD      64
#define CONVD   1664      // DINNER + 2*DSTATE
#define DINPROJ 3224      // 2*DINNER + 2*DSTATE + NH
#define SEQ     4096
#define BSZ     2
#define NTOK    8192      // BSZ*SEQ
#define NCHUNK  64        // SEQ/64
#define EPSF    1e-5f
#define LP      72        // LDS pitch (shorts) for SSD kernels

typedef __attribute__((ext_vector_type(8))) short  short8;
typedef __attribute__((ext_vector_type(4))) float  f32x4;

// ---------------- helpers ----------------
__device__ __forceinline__ unsigned short f2bf(float f) {
  union { float f; unsigned int u; } v; v.f = f;
  unsigned int r = v.u + 0x7fffu + ((v.u >> 16) & 1u);   // RNE
  return (unsigned short)(r >> 16);
}
__device__ __forceinline__ float bf2f(unsigned short u) {
  union { unsigned int i; float f; } v; v.i = ((unsigned int)u) << 16; return v.f;
}
__device__ __forceinline__ float sigm(float x) { return 1.f / (1.f + __expf(-x)); }

// async 16B global -> LDS (lane i of the wave lands at ldsbase + i*16)
__device__ __forceinline__ void gld16(const unsigned short* g, unsigned short* l) {
  __builtin_amdgcn_global_load_lds(
      (const __attribute__((address_space(1))) unsigned int*)g,
      (__attribute__((address_space(3))) unsigned int*)l, 16, 0, 0);
}

// ---------------- LayerNorm -> bf16 ----------------
__global__ __launch_bounds__(256) void k_ln(const float* __restrict__ x,
    const float* __restrict__ w, const float* __restrict__ b,
    unsigned short* __restrict__ xn)
{
  __shared__ float red[4];
  const int row = blockIdx.x, tid = threadIdx.x;
  const float* xr = x + (size_t)row * DMODEL;
  float v[3]; float s = 0.f;
  #pragma unroll
  for (int q = 0; q < 3; q++) { v[q] = xr[q*256 + tid]; s += v[q]; }
  #pragma unroll
  for (int off = 32; off; off >>= 1) s += __shfl_down(s, off);
  if ((tid & 63) == 0) red[tid >> 6] = s;
  __syncthreads();
  const float mu = (red[0] + red[1] + red[2] + red[3]) * (1.f / DMODEL);
  __syncthreads();
  float s2 = 0.f;
  #pragma unroll
  for (int q = 0; q < 3; q++) { float d = v[q] - mu; s2 += d * d; }
  #pragma unroll
  for (int off = 32; off; off >>= 1) s2 += __shfl_down(s2, off);
  if ((tid & 63) == 0) red[tid >> 6] = s2;
  __syncthreads();
  const float rs = rsqrtf((red[0] + red[1] + red[2] + red[3]) * (1.f / DMODEL) + EPSF);
  unsigned short* xo = xn + (size_t)row * DMODEL;
  #pragma unroll
  for (int q = 0; q < 3; q++) {
    int col = q*256 + tid;
    xo[col] = f2bf((v[q] - mu) * rs * w[col] + b[col]);
  }
}

// ---------------- W[K][N] fp32 -> Wt[N][K] bf16 (tiled transpose) ----------------
__global__ __launch_bounds__(256) void k_wtrans(const float* __restrict__ W,
    unsigned short* __restrict__ Wt, int K, int N)
{
  __shared__ float tile[32][33];
  const int tid = threadIdx.x;
  const int tx = tid & 31, ty = tid >> 5;           // 32 x 8
  const int n0 = blockIdx.x * 32, k0 = blockIdx.y * 32;
  #pragma unroll
  for (int r = 0; r < 4; r++) {
    int k = k0 + ty + 8*r;
    if (k < K && n0 + tx < N) tile[ty + 8*r][tx] = W[(size_t)k * N + n0 + tx];
  }
  __syncthreads();
  #pragma unroll
  for (int r = 0; r < 4; r++) {
    int n = n0 + ty + 8*r, k = k0 + tx;
    if (n < N && k < K) Wt[(size_t)n * K + k] = f2bf(tile[tx][ty + 8*r]);
  }
}

// ======== shared GEMM core: C[M][N] = A[M][K] @ Bt[N][K]^T, BK=64, 128x128 tile ==
// LDS swizzle: slot j of row r holds k-granule g = j ^ (r&7)  (granule = 16B).
// epi: 0 plain, 1 sigmoid(C+bias[n]), 2 C+bias[n]+resid[m][n].  Cb!=null -> bf16 out.
__device__ __forceinline__ void gemm_core(const unsigned short* __restrict__ A,
    const unsigned short* __restrict__ Bt, float* __restrict__ C,
    unsigned short* __restrict__ Cb,
    int M, int N, int K, int epi, const float* __restrict__ bias,
    const float* __restrict__ resid, int m0, int n0,
    unsigned short* As, unsigned short* Bs)
{
  const int tid = threadIdx.x;
  const int lane = tid & 63, w = tid >> 6;
  const int wm = (w >> 1) * 64, wn = (w & 1) * 64;
  const int l15 = lane & 15, lq = lane >> 4;
  const int sw = l15 & 7;                  // fragment-read swizzle
  f32x4 acc[4][4];
  #pragma unroll
  for (int i = 0; i < 4; i++)
    #pragma unroll
    for (int j = 0; j < 4; j++) acc[i][j] = (f32x4){0.f, 0.f, 0.f, 0.f};

  // staging geometry: per operand 1024 granules = 4 rounds x 4 waves x 64 lanes
  int rowg[4], gq[4];
  #pragma unroll
  for (int r = 0; r < 4; r++) {
    int gi = (r * 4 + w) * 64 + lane;
    rowg[r] = gi >> 3;
    gq[r] = (gi & 7) ^ (rowg[r] & 7);
  }

  for (int k0 = 0; k0 < K; k0 += 64) {
    __syncthreads();
    #pragma unroll
    for (int r = 0; r < 4; r++)
      gld16(A + (size_t)(m0 + rowg[r]) * K + k0 + gq[r] * 8, &As[(r * 4 + w) * 512]);
    #pragma unroll
    for (int r = 0; r < 4; r++) {
      int nr = n0 + rowg[r]; if (nr >= N) nr = N - 1;   // clamp; cols >= N masked in epilogue
      gld16(Bt + (size_t)nr * K + k0 + gq[r] * 8, &Bs[(r * 4 + w) * 512]);
    }
    __syncthreads();
    #pragma unroll
    for (int ks = 0; ks < 2; ks++) {
      short8 a8[4], b8[4];
      #pragma unroll
      for (int mi = 0; mi < 4; mi++)
        a8[mi] = *(const short8*)(&As[(wm + 16 * mi + l15) * 64 + ((lq + 4 * ks) ^ sw) * 8]);
      #pragma unroll
      for (int ni = 0; ni < 4; ni++)
        b8[ni] = *(const short8*)(&Bs[(wn + 16 * ni + l15) * 64 + ((lq + 4 * ks) ^ sw) * 8]);
      #pragma unroll
      for (int mi = 0; mi < 4; mi++)
        #pragma unroll
        for (int ni = 0; ni < 4; ni++)
          acc[mi][ni] = __builtin_amdgcn_mfma_f32_16x16x32_bf16(a8[mi], b8[ni], acc[mi][ni], 0, 0, 0);
    }
  }
  #pragma unroll
  for (int mi = 0; mi < 4; mi++) {
    #pragma unroll
    for (int r = 0; r < 4; r++) {
      int row = m0 + wm + 16*mi + lq*4 + r;
      #pragma unroll
      for (int ni = 0; ni < 4; ni++) {
        int col = n0 + wn + 16*ni + l15;
        if (col < N) {
          float vv = acc[mi][ni][r];
          if (epi == 1)      vv = sigm(vv + bias[col]);
          else if (epi == 2) vv = vv + bias[col] + resid[(size_t)row * N + col];
          if (Cb) Cb[(size_t)row * N + col] = f2bf(vv);
          else    C [(size_t)row * N + col] = vv;
        }
      }
    }
  }
}

__global__ __launch_bounds__(256) void k_gemm(const unsigned short* __restrict__ A,
    const unsigned short* __restrict__ Bt, float* __restrict__ C,
    unsigned short* __restrict__ Cb,
    int M, int N, int K, int epi, const float* __restrict__ bias,
    const float* __restrict__ resid)
{
  __shared__ alignas(16) unsigned short As[128 * 64];
  __shared__ alignas(16) unsigned short Bs[128 * 64];
  gemm_core(A, Bt, C, Cb, M, N, K, epi, bias, resid,
            blockIdx.y * 128, blockIdx.x * 128, As, Bs);
}

// two independent GEMMs in one dispatch (z-plane) to fill the machine:
// z=0: out_proj  YN @ WOPT -> YPROJ (f32, K=1536)
// z=1: gate      XN @ WGT  -> GATE  (f32, K=768, sigmoid+bias)
__global__ __launch_bounds__(256) void k_dualgemm(
    const unsigned short* __restrict__ A0, const unsigned short* __restrict__ B0,
    float* __restrict__ C0, int K0,
    const unsigned short* __restrict__ A1, const unsigned short* __restrict__ B1,
    float* __restrict__ C1, int K1, const float* __restrict__ bias1, int N)
{
  __shared__ alignas(16) unsigned short As[128 * 64];
  __shared__ alignas(16) unsigned short Bs[128 * 64];
  if (blockIdx.z == 0)
    gemm_core(A0, B0, C0, nullptr, NTOK, N, K0, 0, nullptr, nullptr,
              blockIdx.y * 128, blockIdx.x * 128, As, Bs);
  else
    gemm_core(A1, B1, C1, nullptr, NTOK, N, K1, 1, bias1, nullptr,
              blockIdx.y * 128, blockIdx.x * 128, As, Bs);
}

// ---------------- causal conv1d (K=4) + SiLU over xBC cols (bf16 in/out) ---------
__global__ __launch_bounds__(256) void k_conv(const unsigned short* __restrict__ zx,
    const float* __restrict__ cw, const float* __restrict__ cb,
    unsigned short* __restrict__ out)
{
  size_t idx = (size_t)blockIdx.x * 256 + threadIdx.x;   // NTOK*CONVD total
  int c = (int)(idx % CONVD);
  size_t bt = idx / CONVD;
  int t = (int)(bt % SEQ);
  const unsigned short* base = zx + bt * DINPROJ + DINNER + c;
  float acc = cb[c];
  #pragma unroll
  for (int k = 0; k < 4; k++) {
    int tt = t - 3 + k;
    if (tt >= 0) acc += bf2f(base[(ptrdiff_t)(k - 3) * DINPROJ]) * cw[c * 4 + k];
  }
  out[bt * CONVD + c] = f2bf(acc * sigm(acc));
}

// ---------------- SSD pass 1 (MFMA): S[bh,c][n][p] = sum_s (B[s][n]*wv[s]) X[s][p]
__global__ __launch_bounds__(256) void k_chunkstate(const unsigned short* __restrict__ zx,
    const unsigned short* __restrict__ xbcc, const float* __restrict__ dt_bias,
    const float* __restrict__ A_log, float* __restrict__ S, float* __restrict__ CD)
{
  const int c = blockIdx.x, bh = blockIdx.y;
  const int b = bh / NH, h = bh % NH;
  const int tid = threadIdx.x;
  const int lane = tid & 63, w = tid >> 6;
  const int l15 = lane & 15, lq = lane >> 4;
  __shared__ float wv_[64];
  __shared__ alignas(16) unsigned short Bwt[64][LP];  // [n][s]
  __shared__ alignas(16) unsigned short Xt [64][LP];  // [p][s]

  if (tid < 64) {                     // wave 0: dt, prefix-scan of Lc
    int t = c * 64 + tid;
    float xx = bf2f(zx[((size_t)(b * SEQ + t)) * DINPROJ + (DINNER + CONVD) + h]) + dt_bias[h];
    float dt_ = (xx > 15.f) ? xx : log1pf(__expf(xx));
    float Ah = -__expf(A_log[h]);
    float v = dt_ * Ah;
    #pragma unroll
    for (int off = 1; off < 64; off <<= 1) {
      float u = __shfl_up(v, off);
      if (tid >= off) v += u;
    }
    float L63 = __shfl(v, 63);
    wv_[tid] = __expf(L63 - v) * dt_;
    if (tid == 63) CD[bh * 64 + c] = __expf(v);
  }
  unsigned long long braw[4];
  #pragma unroll
  for (int it = 0; it < 4; it++) {
    int i4 = tid + 256 * it;
    int rr = i4 >> 4, q4 = (i4 & 15) * 4;
    size_t rb = ((size_t)(b * SEQ) + c * 64 + rr) * CONVD;
    braw[it] = *(const unsigned long long*)(xbcc + rb + DINNER + q4);
    unsigned short xs[4];
    *(unsigned long long*)xs = *(const unsigned long long*)(xbcc + rb + h * HD + q4);
    Xt[q4+0][rr] = xs[0]; Xt[q4+1][rr] = xs[1]; Xt[q4+2][rr] = xs[2]; Xt[q4+3][rr] = xs[3];
  }
  __syncthreads();
  #pragma unroll
  for (int it = 0; it < 4; it++) {
    int i4 = tid + 256 * it;
    int rr = i4 >> 4, q4 = (i4 & 15) * 4;
    float wsc = wv_[rr];
    unsigned short us[4];
    *(unsigned long long*)us = braw[it];
    Bwt[q4+0][rr] = f2bf(bf2f(us[0]) * wsc);
    Bwt[q4+1][rr] = f2bf(bf2f(us[1]) * wsc);
    Bwt[q4+2][rr] = f2bf(bf2f(us[2]) * wsc);
    Bwt[q4+3][rr] = f2bf(bf2f(us[3]) * wsc);
  }
  __syncthreads();
  const int n0 = 16 * w;
  short8 a0 = *(const short8*)(&Bwt[n0 + l15][lq * 8]);
  short8 a1 = *(const short8*)(&Bwt[n0 + l15][32 + lq * 8]);
  size_t sb = ((size_t)bh * 64 + c) * 4096;
  #pragma unroll
  for (int pt = 0; pt < 4; pt++) {
    f32x4 acc = (f32x4){0.f, 0.f, 0.f, 0.f};
    short8 b0 = *(const short8*)(&Xt[16*pt + l15][lq * 8]);
    short8 b1 = *(const short8*)(&Xt[16*pt + l15][32 + lq * 8]);
    acc = __builtin_amdgcn_mfma_f32_16x16x32_bf16(a0, b0, acc, 0, 0, 0);
    acc = __builtin_amdgcn_mfma_f32_16x16x32_bf16(a1, b1, acc, 0, 0, 0);
    #pragma unroll
    for (int r = 0; r < 4; r++) {
      int n = n0 + 4*lq + r, p = 16*pt + l15;
      S[sb + (size_t)n * 64 + p] = acc[r];
    }
  }
}

// ---------------- SSD pass 2: chunk-level recurrence (in-place S -> G) -----------
__global__ __launch_bounds__(256) void k_chunkrec(float* __restrict__ S,
    const float* __restrict__ CD)
{
  const int bh = blockIdx.x >> 4, part = blockIdx.x & 15;
  const int e = part * 256 + threadIdx.x;
  float g = 0.f;
  size_t base = (size_t)bh * 64 * 4096 + e;
  for (int c = 0; c < 64; c++) {
    size_t ad = base + (size_t)c * 4096;
    float sv = S[ad];
    float pc = CD[bh * 64 + c];
    S[ad] = g;               // slot c now holds G_c (state before chunk c)
    g = pc * g + sv;
  }
}

// ---------------- SSD pass 3 (MFMA): per-chunk outputs (bf16 Y out) --------------
__global__ __launch_bounds__(256) void k_chunkout(const unsigned short* __restrict__ zx,
    const unsigned short* __restrict__ xbcc, const float* __restrict__ S,
    const float* __restrict__ dt_bias, const float* __restrict__ A_log,
    const float* __restrict__ Dp, unsigned short* __restrict__ Y)
{
  const int c = blockIdx.x, bh = blockIdx.y;
  const int b = bh / NH, h = bh % NH;
  const int tid = threadIdx.x;
  const int lane = tid & 63, w = tid >> 6;
  const int l15 = lane & 15, lq = lane >> 4;
  __shared__ float dts[64], Lc[64], ein[64];
  __shared__ alignas(16) unsigned short Cs  [64][LP];  // [i][n]
  __shared__ alignas(16) unsigned short BsPs[64][LP];  // [s][n], then P[i][s]
  __shared__ alignas(16) unsigned short Xt  [64][LP];  // [p][s]
  __shared__ alignas(16) unsigned short Gt  [64][LP];  // [p][n]

  if (tid < 64) {                     // wave 0: dt, prefix-scan of Lc
    int t = c * 64 + tid;
    float xx = bf2f(zx[((size_t)(b * SEQ + t)) * DINPROJ + (DINNER + CONVD) + h]) + dt_bias[h];
    float dt_ = (xx > 15.f) ? xx : log1pf(__expf(xx));
    dts[tid] = dt_;
    float Ah = -__expf(A_log[h]);
    float v = dt_ * Ah;
    #pragma unroll
    for (int off = 1; off < 64; off <<= 1) {
      float u = __shfl_up(v, off);
      if (tid >= off) v += u;
    }
    Lc[tid] = v;
    ein[tid] = __expf(v);
  }
  const size_t gslot = ((size_t)bh * 64 + c) * 4096;
  #pragma unroll
  for (int it = 0; it < 4; it++) {
    int i4 = tid + 256 * it;
    int rr = i4 >> 4, q4 = (i4 & 15) * 4;
    size_t rb = ((size_t)(b * SEQ) + c * 64 + rr) * CONVD;
    *(unsigned long long*)(&Cs[rr][q4])   = *(const unsigned long long*)(xbcc + rb + (DINNER + DSTATE) + q4);
    *(unsigned long long*)(&BsPs[rr][q4]) = *(const unsigned long long*)(xbcc + rb + DINNER + q4);
    unsigned short xs[4];
    *(unsigned long long*)xs = *(const unsigned long long*)(xbcc + rb + h * HD + q4);
    Xt[q4+0][rr] = xs[0]; Xt[q4+1][rr] = xs[1]; Xt[q4+2][rr] = xs[2]; Xt[q4+3][rr] = xs[3];
    float4 vG = *(const float4*)(S + gslot + (size_t)i4 * 4);   // row n=rr, cols q4..q4+3
    Gt[q4+0][rr] = f2bf(vG.x); Gt[q4+1][rr] = f2bf(vG.y);
    Gt[q4+2][rr] = f2bf(vG.z); Gt[q4+3][rr] = f2bf(vG.w);
  }
  __syncthreads();
  // ---- matmul1: G[i][s] = sum_n C[i][n] B[s][n]; apply causal decay mask -> P ----
  const int i0 = 16 * w;
  short8 ac0 = *(const short8*)(&Cs[i0 + l15][lq * 8]);
  short8 ac1 = *(const short8*)(&Cs[i0 + l15][32 + lq * 8]);
  float pp[4][4];
  #pragma unroll
  for (int st = 0; st < 4; st++) {
    f32x4 g = (f32x4){0.f, 0.f, 0.f, 0.f};
    if (st <= w) {                                   // wave-uniform causal skip
      short8 b0 = *(const short8*)(&BsPs[16*st + l15][lq * 8]);
      short8 b1 = *(const short8*)(&BsPs[16*st + l15][32 + lq * 8]);
      g = __builtin_amdgcn_mfma_f32_16x16x32_bf16(ac0, b0, g, 0, 0, 0);
      g = __builtin_amdgcn_mfma_f32_16x16x32_bf16(ac1, b1, g, 0, 0, 0);
    }
    #pragma unroll
    for (int r = 0; r < 4; r++) {
      int i = i0 + 4*lq + r, s = 16*st + l15;
      pp[st][r] = (s <= i) ? g[r] * __expf(Lc[i] - Lc[s]) * dts[s] : 0.f;
    }
  }
  __syncthreads();                                   // all waves done reading Bs
  #pragma unroll
  for (int st = 0; st < 4; st++)
    #pragma unroll
    for (int r = 0; r < 4; r++)
      BsPs[i0 + 4*lq + r][16*st + l15] = f2bf(pp[st][r]);   // P[i][s], s contiguous
  __syncthreads();
  // ---- matmul2+3: Y[i][p] = P@X + ein[i]*(C@G) + D*x ----
  short8 ap0 = *(const short8*)(&BsPs[i0 + l15][lq * 8]);
  short8 ap1 = *(const short8*)(&BsPs[i0 + l15][32 + lq * 8]);
  const float Dh = Dp[h];
  #pragma unroll
  for (int pt = 0; pt < 4; pt++) {
    const int p0 = 16 * pt;
    f32x4 y1 = (f32x4){0.f, 0.f, 0.f, 0.f};
    f32x4 y2 = (f32x4){0.f, 0.f, 0.f, 0.f};
    short8 bx0 = *(const short8*)(&Xt[p0 + l15][lq * 8]);
    y1 = __builtin_amdgcn_mfma_f32_16x16x32_bf16(ap0, bx0, y1, 0, 0, 0);
    if (w >= 2) {                                    // P rows of wave w have k < 16(w+1)
      short8 bx1 = *(const short8*)(&Xt[p0 + l15][32 + lq * 8]);
      y1 = __builtin_amdgcn_mfma_f32_16x16x32_bf16(ap1, bx1, y1, 0, 0, 0);
    }
    short8 bg0 = *(const short8*)(&Gt[p0 + l15][lq * 8]);
    short8 bg1 = *(const short8*)(&Gt[p0 + l15][32 + lq * 8]);
    y2 = __builtin_amdgcn_mfma_f32_16x16x32_bf16(ac0, bg0, y2, 0, 0, 0);
    y2 = __builtin_amdgcn_mfma_f32_16x16x32_bf16(ac1, bg1, y2, 0, 0, 0);
    #pragma unroll
    for (int r = 0; r < 4; r++) {
      int i = i0 + 4*lq + r, p = p0 + l15;
      float xv = bf2f(Xt[p][i]);
      float o = y1[r] + ein[i] * y2[r] + Dh * xv;
      Y[((size_t)(b * SEQ) + c * 64 + i) * DINNER + h * HD + p] = f2bf(o);
    }
  }
}

// ---------------- y*silu(z), RMSNorm -> bf16 -------------------------------------
__global__ __launch_bounds__(256) void k_fuse(const unsigned short* __restrict__ Y,
    const unsigned short* __restrict__ ZX, const float* __restrict__ rw,
    unsigned short* __restrict__ YN)
{
  __shared__ float red[4];
  const int row = blockIdx.x, tid = threadIdx.x;
  const unsigned short* yr = Y + (size_t)row * DINNER;
  const unsigned short* zr = ZX + (size_t)row * DINPROJ;
  float v[6]; float s2 = 0.f;
  #pragma unroll
  for (int q = 0; q < 6; q++) {
    int col = q * 256 + tid;
    float z = bf2f(zr[col]);
    float yv = bf2f(yr[col]) * (z * sigm(z));
    v[q] = yv; s2 += yv * yv;
  }
  #pragma unroll
  for (int off = 32; off; off >>= 1) s2 += __shfl_down(s2, off);
  if ((tid & 63) == 0) red[tid >> 6] = s2;
  __syncthreads();
  const float rs = rsqrtf((red[0] + red[1] + red[2] + red[3]) * (1.f / DINNER) + EPSF);
  unsigned short* yo = YN + (size_t)row * DINNER;
  #pragma unroll
  for (int q = 0; q < 6; q++) {
    int col = q * 256 + tid;
    yo[col] = f2bf(v[q] * rs * rw[col]);
  }
}

// ---------------- yg = bf16(yproj * gate) ----------------------------------------
__global__ __launch_bounds__(256) void k_gatemul(const float* __restrict__ YP,
    const float* __restrict__ G, unsigned short* __restrict__ YG)
{
  size_t idx = (size_t)blockIdx.x * 256 + threadIdx.x;
  YG[idx] = f2bf(YP[idx] * G[idx]);
}

// ---------------- launch ----------------------------------------------------------
extern "C" void kernel_launch(void* const* d_in, const int* in_sizes, int n_in,
                              void* d_out, int out_size, void* d_ws, size_t ws_size,
                              hipStream_t stream)
{
  const float* x         = (const float*)d_in[0];
  const float* ln_w      = (const float*)d_in[1];
  const float* ln_b      = (const float*)d_in[2];
  const float* in_proj_w = (const float*)d_in[3];
  const float* conv_w    = (const float*)d_in[4];
  const float* conv_b    = (const float*)d_in[5];
  const float* dt_bias   = (const float*)d_in[6];
  const float* A_log     = (const float*)d_in[7];
  const float* D_param   = (const float*)d_in[8];
  const float* rms_w     = (const float*)d_in[9];
  const float* out_proj_w= (const float*)d_in[10];
  const float* gate_w    = (const float*)d_in[11];
  const float* gate_b    = (const float*)d_in[12];
  const float* out_w     = (const float*)d_in[13];
  const float* out_b     = (const float*)d_in[14];
  float* out = (float*)d_out;
  char* ws = (char*)d_ws;

  // ---- workspace layout (bytes). peak = 177,848,320 B (~170 MB) ----
  const size_t WS_NEEDED = 177848320ull;
  if (ws_size < WS_NEEDED) return;

  unsigned short* XN    = (unsigned short*)(ws + 0);
  unsigned short* WIT   = (unsigned short*)(ws + 12582912);
  unsigned short* WGT   = (unsigned short*)(ws + 17534976);
  unsigned short* WOPT  = (unsigned short*)(ws + 18714624);
  unsigned short* WOT   = (unsigned short*)(ws + 21073920);
  unsigned short* ZXb   = (unsigned short*)(ws + 22253568);   // 8192x3224 bf16
  unsigned short* XBCCb = (unsigned short*)(ws + 75075584);   // 8192x1664 bf16
  float*          SG    = (float*)(ws + 102338560);           // 3072x4096 f32
  float*          CD    = (float*)(ws + 152670208);           // 3072 f32
  unsigned short* Yb    = (unsigned short*)(ws + 152682496);  // 8192x1536 bf16
  // overlays:
  unsigned short* YN    = (unsigned short*)(ws + 102338560);  // in SG region (dead after chunkout)
  float*          GATE  = (float*)(ws + 22253568);            // in ZXb region (dead after fuse)
  float*          YPROJ = (float*)(ws + 47419392);            // in ZXb region
  unsigned short* YG    = (unsigned short*)(ws + 75075584);   // in XBCCb region (dead after chunkout)

  // 1) weight converts (bf16, transposed for TN GEMM)
  k_wtrans<<<dim3(101, 24), 256, 0, stream>>>(in_proj_w,  WIT,  768,  3224);
  k_wtrans<<<dim3(24, 24),  256, 0, stream>>>(gate_w,     WGT,  768,  768);
  k_wtrans<<<dim3(24, 48),  256, 0, stream>>>(out_proj_w, WOPT, 1536, 768);
  k_wtrans<<<dim3(24, 24),  256, 0, stream>>>(out_w,      WOT,  768,  768);
  // 2) layernorm
  k_ln<<<NTOK, 256, 0, stream>>>(x, ln_w, ln_b, XN);
  // 3) in_proj GEMM -> zxbcdt (bf16)
  k_gemm<<<dim3(26, 64), 256, 0, stream>>>(XN, WIT, nullptr, ZXb, NTOK, DINPROJ, DMODEL, 0, nullptr, nullptr);
  // 4) causal conv + silu (bf16 -> bf16)
  k_conv<<<(NTOK * CONVD) / 256, 256, 0, stream>>>(ZXb, conv_w, conv_b, XBCCb);
  // 5-7) SSD scan
  k_chunkstate<<<dim3(NCHUNK, BSZ * NH), 256, 0, stream>>>(ZXb, XBCCb, dt_bias, A_log, SG, CD);
  k_chunkrec<<<BSZ * NH * 16, 256, 0, stream>>>(SG, CD);
  k_chunkout<<<dim3(NCHUNK, BSZ * NH), 256, 0, stream>>>(ZXb, XBCCb, SG, dt_bias, A_log, D_param, Yb);
  // 8) y*silu(z) + RMSNorm -> bf16 (YN lands in dead SG region)
  k_fuse<<<NTOK, 256, 0, stream>>>(Yb, ZXb, rms_w, YN);
  // 9+10) gate GEMM (sigmoid) + out_proj GEMM, one dispatch (z-planes)
  k_dualgemm<<<dim3(6, 64, 2), 256, 0, stream>>>(YN, WOPT, YPROJ, DINNER,
                                                 XN, WGT, GATE, DMODEL, gate_b, DMODEL);
  // 11) gate multiply -> bf16
  k_gatemul<<<(NTOK * DMODEL) / 256, 256, 0, stream>>>(YPROJ, GATE, YG);
  // 12) final GEMM + bias + residual -> d_out
  k_gemm<<<dim3(6, 64), 256, 0, stream>>>(YG, WOT, out, nullptr, NTOK, DMODEL, DMODEL, 2, out_b, x);
}